// Round 3
// baseline (156.325 us; speedup 1.0000x reference)
//
#include <hip/hip_runtime.h>
#include <hip/hip_bf16.h>

#define BT 16384      // B*T rows
#define CDIM 1024
#define HD 64
#define TT 4096
#define NSPLIT 4

typedef __bf16 bf16x8 __attribute__((ext_vector_type(8)));
typedef __bf16 bf16x4 __attribute__((ext_vector_type(4)));
typedef float f32x4 __attribute__((ext_vector_type(4)));

__device__ __forceinline__ f32x4 mfma16(bf16x8 a, bf16x8 b, f32x4 c){
  return __builtin_amdgcn_mfma_f32_16x16x32_bf16(a, b, c, 0, 0, 0);
}

// ---------- kernel 1: weights -> bf16 [192][1024]; rows 64..127 (Wq) pre-scaled by 1/8
__global__ __launch_bounds__(256) void wconv_k(const float* __restrict__ Wk,
    const float* __restrict__ Wq, const float* __restrict__ Wv,
    __bf16* __restrict__ Wbf){
  int idx = blockIdx.x*256 + threadIdx.x;
  int e0 = idx*4;
  int n = e0 >> 10;
  int c = e0 & 1023;
  const float* src; float s;
  if (n < 64)      { src = Wk + (size_t)n*CDIM;       s = 1.0f;   }
  else if (n < 128){ src = Wq + (size_t)(n-64)*CDIM;  s = 0.125f; }
  else             { src = Wv + (size_t)(n-128)*CDIM; s = 1.0f;   }
  float4 v = *reinterpret_cast<const float4*>(src + c);
  __bf16* dst = Wbf + e0;
  dst[0]=(__bf16)(v.x*s); dst[1]=(__bf16)(v.y*s);
  dst[2]=(__bf16)(v.z*s); dst[3]=(__bf16)(v.w*s);
}

// ---------- kernel 2: projections. k,q row-major [BT][64]; v transposed [B][64][T].
__global__ __launch_bounds__(256) void proj_k(const float* __restrict__ x,
    const __bf16* __restrict__ Wbf, __bf16* __restrict__ kb,
    __bf16* __restrict__ qb, __bf16* __restrict__ vTb){
  const int tid  = threadIdx.x;
  const int lane = tid & 63;
  const int w    = tid >> 6;
  const int l15  = lane & 15, g = lane >> 4;
  const long rowbase = (long)blockIdx.x*64 + w*16;

  f32x4 acc[12];
  #pragma unroll
  for (int j=0;j<12;j++) acc[j] = (f32x4)(0.0f);

  const float* xrow = x + (rowbase + l15)*CDIM;
  float4 clo = *reinterpret_cast<const float4*>(xrow + g*8);
  float4 chi = *reinterpret_cast<const float4*>(xrow + g*8 + 4);
  for (int it=0; it<32; ++it){
    const int nk0 = (it < 31) ? (it+1)*32 + g*8 : it*32 + g*8;  // clamp last
    float4 nlo = *reinterpret_cast<const float4*>(xrow + nk0);
    float4 nhi = *reinterpret_cast<const float4*>(xrow + nk0 + 4);
    bf16x8 a;
    a[0]=(__bf16)clo.x; a[1]=(__bf16)clo.y; a[2]=(__bf16)clo.z; a[3]=(__bf16)clo.w;
    a[4]=(__bf16)chi.x; a[5]=(__bf16)chi.y; a[6]=(__bf16)chi.z; a[7]=(__bf16)chi.w;
    const int kk0 = it*32 + g*8;
    #pragma unroll
    for (int nc=0; nc<12; ++nc){
      bf16x8 b = *reinterpret_cast<const bf16x8*>(Wbf + (size_t)(nc*16 + l15)*CDIM + kk0);
      acc[nc] = mfma16(a, b, acc[nc]);
    }
    clo = nlo; chi = nhi;
  }

  const long row0 = rowbase + g*4;
  #pragma unroll
  for (int nc=0; nc<12; ++nc){
    const int mat = nc >> 2;              // 0=k, 1=q, 2=v
    const int h   = (nc & 3)*16 + l15;
    if (mat == 0){
      __bf16* dst = kb + row0*HD + h;
      #pragma unroll
      for (int r=0;r<4;r++) dst[r*HD] = (__bf16)acc[nc][r];
    } else if (mat == 1){
      __bf16* dst = qb + row0*HD + h;
      #pragma unroll
      for (int r=0;r<4;r++) dst[r*HD] = (__bf16)acc[nc][r];
    } else {
      const long bidx = row0 >> 12;       // batch
      const long t0   = row0 & 4095;
      bf16x4 t4;
      #pragma unroll
      for (int r=0;r<4;r++) t4[r] = (__bf16)acc[nc][r];
      *reinterpret_cast<bf16x4*>(vTb + (bidx*64 + h)*TT + t0) = t4;
    }
  }
}

// ---------- kernel 3: causal flash attention, KV-split partials, barrier-free.
// grid = B * 64 qtiles * NSPLIT = 1024 blocks, 256 thr (4 independent waves).
__global__ __launch_bounds__(256) void attn_part_k(const __bf16* __restrict__ kbg,
    const __bf16* __restrict__ qbg, const __bf16* __restrict__ vT,
    __bf16* __restrict__ po, float2* __restrict__ pml){
  __shared__ __bf16 Plds[4][16][72];      // per-wave P round-trip only

  const int tid  = threadIdx.x;
  const int lane = tid & 63;
  const int w    = tid >> 6;
  const int l15  = lane & 15, g = lane >> 4;

  const int bi  = blockIdx.x;
  const int b   = bi >> 8;
  const int rem = bi & 255;
  const int qt  = 63 - (rem >> 2);        // longest blocks dispatch first
  const int s   = rem & 3;

  const int ntiles = qt + 1;
  const int lo = ( s      * ntiles) >> 2;
  const int hi = ((s + 1) * ntiles) >> 2;
  const int pidx = (b*64 + qt)*NSPLIT + s;

  if (lo == hi){
    if (l15 == 0){
      #pragma unroll
      for (int r=0;r<4;r++)
        pml[pidx*64 + w*16 + g*4 + r] = make_float2(-1e30f, 0.0f);
    }
    return;
  }

  const long qbase = (long)b*TT + (long)qt*64;

  bf16x8 qf0, qf1;
  {
    const __bf16* src = qbg + (qbase + w*16 + l15)*HD + g*8;
    qf0 = *reinterpret_cast<const bf16x8*>(src);
    qf1 = *reinterpret_cast<const bf16x8*>(src + 32);
  }

  f32x4 o[4];
  #pragma unroll
  for (int ch=0; ch<4; ++ch) o[ch] = (f32x4)(0.0f);
  float m[4], l[4];
  #pragma unroll
  for (int r=0;r<4;r++){ m[r] = -1e30f; l[r] = 0.0f; }

  const __bf16* vbase = vT + (size_t)b*64*TT;

  for (int kv=lo; kv<hi; ++kv){
    const long kvbase = (long)b*TT + (long)kv*64;
    const int  kvt    = kv*64;

    // preload V B-frags (contiguous 16B from vT rows); latency hides under QK+softmax
    bf16x8 vb[4][2];
    #pragma unroll
    for (int ch=0; ch<4; ++ch){
      const __bf16* vr = vbase + (size_t)(ch*16 + l15)*TT + kvt + g*8;
      vb[ch][0] = *reinterpret_cast<const bf16x8*>(vr);
      vb[ch][1] = *reinterpret_cast<const bf16x8*>(vr + 32);
    }

    // S = Q K^T : K B-frags direct from global (row-major matches B layout)
    f32x4 sv[4];
    #pragma unroll
    for (int c=0;c<4;c++){
      const __bf16* kr = kbg + (kvbase + c*16 + l15)*HD + g*8;
      bf16x8 kb0 = *reinterpret_cast<const bf16x8*>(kr);
      bf16x8 kb1 = *reinterpret_cast<const bf16x8*>(kr + 32);
      sv[c] = mfma16(qf0, kb0, (f32x4)(0.0f));
      sv[c] = mfma16(qf1, kb1, sv[c]);
    }

    if (kv == qt){   // diagonal tile: causal mask
      #pragma unroll
      for (int c=0;c<4;c++){
        const int key = c*16 + l15;
        #pragma unroll
        for (int r=0;r<4;r++){
          const int qr = w*16 + g*4 + r;
          if (key > qr) sv[c][r] = -1e30f;
        }
      }
    }

    float alpha[4];
    #pragma unroll
    for (int r=0;r<4;r++){
      float pm = fmaxf(fmaxf(sv[0][r], sv[1][r]), fmaxf(sv[2][r], sv[3][r]));
      pm = fmaxf(pm, __shfl_xor(pm, 1));
      pm = fmaxf(pm, __shfl_xor(pm, 2));
      pm = fmaxf(pm, __shfl_xor(pm, 4));
      pm = fmaxf(pm, __shfl_xor(pm, 8));
      const float mn = fmaxf(m[r], pm);
      alpha[r] = __expf(m[r] - mn);
      m[r] = mn;
    }
    #pragma unroll
    for (int c=0;c<4;c++){
      #pragma unroll
      for (int r=0;r<4;r++) sv[c][r] = __expf(sv[c][r] - m[r]);
    }
    #pragma unroll
    for (int r=0;r<4;r++){
      float rs = sv[0][r] + sv[1][r] + sv[2][r] + sv[3][r];
      rs += __shfl_xor(rs, 1);
      rs += __shfl_xor(rs, 2);
      rs += __shfl_xor(rs, 4);
      rs += __shfl_xor(rs, 8);
      l[r] = l[r]*alpha[r] + rs;
    }
    #pragma unroll
    for (int ch=0; ch<4; ++ch){
      #pragma unroll
      for (int r=0;r<4;r++) o[ch][r] *= alpha[r];
    }

    // P -> per-wave LDS (C-layout) -> A-frags; wave-synchronous, no block barrier
    #pragma unroll
    for (int c=0;c<4;c++){
      #pragma unroll
      for (int r=0;r<4;r++) Plds[w][g*4+r][c*16 + l15] = (__bf16)sv[c][r];
    }
    asm volatile("s_waitcnt lgkmcnt(0)" ::: "memory");
    __builtin_amdgcn_sched_barrier(0);
    bf16x8 pa0 = *reinterpret_cast<const bf16x8*>(&Plds[w][l15][g*8]);
    bf16x8 pa1 = *reinterpret_cast<const bf16x8*>(&Plds[w][l15][g*8 + 32]);

    #pragma unroll
    for (int ch=0; ch<4; ++ch){
      o[ch] = mfma16(pa0, vb[ch][0], o[ch]);
      o[ch] = mfma16(pa1, vb[ch][1], o[ch]);
    }
  }

  // epilogue: store NORMALIZED partial o (bf16) + (m,l) f32
  float rl[4];
  #pragma unroll
  for (int r=0;r<4;r++) rl[r] = (l[r] > 0.0f) ? 1.0f/l[r] : 0.0f;
  __bf16* podst = po + (size_t)pidx*4096;
  #pragma unroll
  for (int ch=0; ch<4; ++ch){
    #pragma unroll
    for (int r=0;r<4;r++)
      podst[(w*16 + g*4 + r)*64 + ch*16 + l15] = (__bf16)(o[ch][r] * rl[r]);
  }
  if (l15 == 0){
    #pragma unroll
    for (int r=0;r<4;r++)
      pml[pidx*64 + w*16 + g*4 + r] = make_float2(m[r], l[r]);
  }
}

// ---------- kernel 4: combine partials.
__global__ __launch_bounds__(256) void comb_k(const __bf16* __restrict__ po,
    const float2* __restrict__ pml, float* __restrict__ out){
  const int idx = blockIdx.x*256 + threadIdx.x;
  const int qrow  = idx >> 6;
  const int dim   = idx & 63;
  const int qtg   = qrow >> 6;
  const int rowin = qrow & 63;

  float2 ml[NSPLIT];
  float M = -3e30f;
  #pragma unroll
  for (int s=0;s<NSPLIT;s++){
    ml[s] = pml[(qtg*NSPLIT + s)*64 + rowin];
    M = fmaxf(M, ml[s].x);
  }
  float num = 0.0f, den = 0.0f;
  #pragma unroll
  for (int s=0;s<NSPLIT;s++){
    const float wgt = __expf(ml[s].x - M) * ml[s].y;
    den += wgt;
    num += wgt * (float)po[(size_t)(qtg*NSPLIT + s)*4096 + rowin*64 + dim];
  }
  out[idx] = num / den;
}

extern "C" void kernel_launch(void* const* d_in, const int* in_sizes, int n_in,
                              void* d_out, int out_size, void* d_ws, size_t ws_size,
                              hipStream_t stream) {
  const float* x  = (const float*)d_in[0];
  const float* Wk = (const float*)d_in[2];
  const float* Wq = (const float*)d_in[3];
  const float* Wv = (const float*)d_in[4];
  float* out = (float*)d_out;

  char* ws = (char*)d_ws;
  __bf16* Wbf = (__bf16*)ws;                         // 384 KiB
  __bf16* kb  = (__bf16*)(ws + 393216);              // 2 MiB
  __bf16* qb  = (__bf16*)(ws + 2490368);             // 2 MiB
  __bf16* vTb = (__bf16*)(ws + 4587520);             // 2 MiB
  __bf16* po  = (__bf16*)(ws + 6684672);             // 8 MiB
  float2* pml = (float2*)(ws + 15073280);            // 512 KiB

  wconv_k    <<<192,  256, 0, stream>>>(Wk, Wq, Wv, Wbf);
  proj_k     <<<256,  256, 0, stream>>>(x, Wbf, kb, qb, vTb);
  attn_part_k<<<1024, 256, 0, stream>>>(kb, qb, vTb, po, pml);
  comb_k     <<<4096, 256, 0, stream>>>(po, pml, out);
}

// Round 4
// 104.006 us; speedup vs baseline: 1.5030x; 1.5030x over previous
//
#include <hip/hip_runtime.h>
#include <hip/hip_bf16.h>

#define BT 16384      // B*T rows
#define CDIM 1024
#define HD 64
#define TT 4096

typedef __bf16 bf16x8 __attribute__((ext_vector_type(8)));
typedef __bf16 bf16x4 __attribute__((ext_vector_type(4)));
typedef float f32x4 __attribute__((ext_vector_type(4)));

__device__ __forceinline__ f32x4 mfma16(bf16x8 a, bf16x8 b, f32x4 c){
  return __builtin_amdgcn_mfma_f32_16x16x32_bf16(a, b, c, 0, 0, 0);
}

// ---------- kernel 1: weights -> bf16 [192][1024]; rows 64..127 (Wq) pre-scaled by 1/8
__global__ __launch_bounds__(256) void wconv_k(const float* __restrict__ Wk,
    const float* __restrict__ Wq, const float* __restrict__ Wv,
    __bf16* __restrict__ Wbf){
  int idx = blockIdx.x*256 + threadIdx.x;
  int e0 = idx*4;
  int n = e0 >> 10;
  int c = e0 & 1023;
  const float* src; float s;
  if (n < 64)      { src = Wk + (size_t)n*CDIM;       s = 1.0f;   }
  else if (n < 128){ src = Wq + (size_t)(n-64)*CDIM;  s = 0.125f; }
  else             { src = Wv + (size_t)(n-128)*CDIM; s = 1.0f;   }
  float4 v = *reinterpret_cast<const float4*>(src + c);
  __bf16* dst = Wbf + e0;
  dst[0]=(__bf16)(v.x*s); dst[1]=(__bf16)(v.y*s);
  dst[2]=(__bf16)(v.z*s); dst[3]=(__bf16)(v.w*s);
}

// ---------- kernel 2: projections, in-block K-split x2.
// 512 thr = 8 waves. waves 0-3: k[0,512) rows rg*16; waves 4-7: k[512,1024).
// combine halves through LDS; waves 4-7 store k,q row-major [BT][64], v transposed [B][64][T].
__global__ __launch_bounds__(512) void proj_k(const float* __restrict__ x,
    const __bf16* __restrict__ Wbf, __bf16* __restrict__ kb,
    __bf16* __restrict__ qb, __bf16* __restrict__ vTb){
  __shared__ float redbuf[64][196];

  const int tid  = threadIdx.x;
  const int lane = tid & 63;
  const int w    = tid >> 6;        // 0..7
  const int half = w >> 2;          // 0 | 1
  const int rg   = w & 3;           // row group 0..3
  const int l15  = lane & 15, g = lane >> 4;
  const long rowbase = (long)blockIdx.x*64 + rg*16;
  const int  kbase   = half*512;

  f32x4 acc[12];
  #pragma unroll
  for (int j=0;j<12;j++) acc[j] = (f32x4)(0.0f);

  const float* xrow = x + (rowbase + l15)*CDIM + kbase;

  // prefetch depth 2
  float4 alo = *reinterpret_cast<const float4*>(xrow + g*8);
  float4 ahi = *reinterpret_cast<const float4*>(xrow + g*8 + 4);
  float4 blo = *reinterpret_cast<const float4*>(xrow + 32 + g*8);
  float4 bhi = *reinterpret_cast<const float4*>(xrow + 32 + g*8 + 4);

  for (int it=0; it<16; ++it){
    const int nk = (it+2 < 16) ? (it+2)*32 : it*32;
    float4 nlo = *reinterpret_cast<const float4*>(xrow + nk + g*8);
    float4 nhi = *reinterpret_cast<const float4*>(xrow + nk + g*8 + 4);

    bf16x8 a;
    a[0]=(__bf16)alo.x; a[1]=(__bf16)alo.y; a[2]=(__bf16)alo.z; a[3]=(__bf16)alo.w;
    a[4]=(__bf16)ahi.x; a[5]=(__bf16)ahi.y; a[6]=(__bf16)ahi.z; a[7]=(__bf16)ahi.w;

    const int kk0 = kbase + it*32 + g*8;
    #pragma unroll
    for (int nc=0; nc<12; ++nc){
      bf16x8 b = *reinterpret_cast<const bf16x8*>(Wbf + (size_t)(nc*16 + l15)*CDIM + kk0);
      acc[nc] = mfma16(a, b, acc[nc]);
    }
    alo = blo; ahi = bhi; blo = nlo; bhi = nhi;
  }

  // half 0 deposits partials, half 1 adds and stores
  if (half == 0){
    #pragma unroll
    for (int nc=0; nc<12; ++nc){
      #pragma unroll
      for (int r=0;r<4;r++)
        redbuf[rg*16 + g*4 + r][nc*16 + l15] = acc[nc][r];
    }
  }
  __syncthreads();
  if (half == 1){
    const long row0 = rowbase + g*4;
    const int  lrow = rg*16 + g*4;
    #pragma unroll
    for (int nc=0; nc<12; ++nc){
      const int mat = nc >> 2;              // 0=k, 1=q, 2=v
      const int h   = (nc & 3)*16 + l15;
      float sum[4];
      #pragma unroll
      for (int r=0;r<4;r++) sum[r] = acc[nc][r] + redbuf[lrow + r][nc*16 + l15];
      if (mat == 0){
        __bf16* dst = kb + row0*HD + h;
        #pragma unroll
        for (int r=0;r<4;r++) dst[r*HD] = (__bf16)sum[r];
      } else if (mat == 1){
        __bf16* dst = qb + row0*HD + h;
        #pragma unroll
        for (int r=0;r<4;r++) dst[r*HD] = (__bf16)sum[r];
      } else {
        const long bidx = row0 >> 12;
        const long t0   = row0 & 4095;
        bf16x4 t4;
        #pragma unroll
        for (int r=0;r<4;r++) t4[r] = (__bf16)sum[r];
        *reinterpret_cast<bf16x4*>(vTb + (bidx*64 + h)*TT + t0) = t4;
      }
    }
  }
}

// ---------- kernel 3: causal flash attention, fixed-max softmax, KV-split partials.
// grid = B * 64 qtiles * NS, 256 thr (4 waves x 16 q-rows). p = exp(s - 16), no max/rescale.
template<int NS>
__global__ __launch_bounds__(256) void attn_part_k(const __bf16* __restrict__ kbg,
    const __bf16* __restrict__ qbg, const __bf16* __restrict__ vT,
    __bf16* __restrict__ po, float* __restrict__ pl){
  __shared__ __bf16 Klds[64][68];     // [key][dim]
  __shared__ __bf16 Vlds[64][68];     // [dim][key]  (from pre-transposed vT)
  __shared__ __bf16 Plds[4][16][68];  // per-wave P round-trip

  const int tid  = threadIdx.x;
  const int lane = tid & 63;
  const int w    = tid >> 6;
  const int l15  = lane & 15, g = lane >> 4;

  const int bi  = blockIdx.x;
  const int b   = bi / (64*NS);
  const int rem = bi % (64*NS);
  const int qt  = 63 - rem / NS;      // longest blocks dispatch first
  const int s   = rem % NS;

  const int ntiles = qt + 1;
  const int lo = ( s      * ntiles) / NS;
  const int hi = ((s + 1) * ntiles) / NS;
  const int pidx = (b*64 + qt)*NS + s;

  if (lo == hi){                      // empty split (block-uniform): weight 0
    if (l15 == 0){
      #pragma unroll
      for (int r=0;r<4;r++) pl[pidx*64 + w*16 + g*4 + r] = 0.0f;
    }
    return;
  }

  const long qbase = (long)b*TT + (long)qt*64;

  bf16x8 qf0, qf1;
  {
    const __bf16* src = qbg + (qbase + w*16 + l15)*HD + g*8;
    qf0 = *reinterpret_cast<const bf16x8*>(src);
    qf1 = *reinterpret_cast<const bf16x8*>(src + 32);
  }

  f32x4 o[4];
  #pragma unroll
  for (int ch=0; ch<4; ++ch) o[ch] = (f32x4)(0.0f);
  float lp[4] = {0.f, 0.f, 0.f, 0.f};

  const __bf16* vbase = vT + (size_t)b*64*TT;

  for (int kv=lo; kv<hi; ++kv){
    const long kvbase = (long)b*TT + (long)kv*64;
    const int  kvt    = kv*64;

    __syncthreads();                  // previous tile fully consumed
    {
      const int key = tid >> 2;
      const int d0  = (tid & 3) * 16;
      const __bf16* ks = kbg + (kvbase + key)*HD + d0;
      *reinterpret_cast<bf16x8*>(&Klds[key][d0])   = *reinterpret_cast<const bf16x8*>(ks);
      *reinterpret_cast<bf16x8*>(&Klds[key][d0+8]) = *reinterpret_cast<const bf16x8*>(ks+8);
      const int h    = tid >> 2;
      const int key0 = (tid & 3) * 16;
      const __bf16* vs = vbase + (size_t)h*TT + kvt + key0;
      *reinterpret_cast<bf16x8*>(&Vlds[h][key0])   = *reinterpret_cast<const bf16x8*>(vs);
      *reinterpret_cast<bf16x8*>(&Vlds[h][key0+8]) = *reinterpret_cast<const bf16x8*>(vs+8);
    }
    __syncthreads();

    // S - 16 = Q K^T - 16 (seed accumulator with -16)
    f32x4 sv[4];
    #pragma unroll
    for (int c=0;c<4;c++){
      bf16x8 kb0 = *reinterpret_cast<const bf16x8*>(&Klds[c*16 + l15][g*8]);
      bf16x8 kb1 = *reinterpret_cast<const bf16x8*>(&Klds[c*16 + l15][g*8 + 32]);
      sv[c] = mfma16(qf0, kb0, (f32x4)(-16.0f));
      sv[c] = mfma16(qf1, kb1, sv[c]);
    }

    if (kv == qt){   // diagonal tile: causal mask
      #pragma unroll
      for (int c=0;c<4;c++){
        const int key = c*16 + l15;
        #pragma unroll
        for (int r=0;r<4;r++){
          const int qr = w*16 + g*4 + r;
          if (key > qr) sv[c][r] = -1e30f;
        }
      }
    }

    // p = exp(s-16); accumulate per-lane row sums (reduced once at end)
    #pragma unroll
    for (int c=0;c<4;c++){
      #pragma unroll
      for (int r=0;r<4;r++) sv[c][r] = __expf(sv[c][r]);
    }
    #pragma unroll
    for (int r=0;r<4;r++)
      lp[r] += (sv[0][r] + sv[1][r]) + (sv[2][r] + sv[3][r]);

    // P -> per-wave LDS (C-layout) -> A-frags (wave-synchronous)
    #pragma unroll
    for (int c=0;c<4;c++){
      #pragma unroll
      for (int r=0;r<4;r++) Plds[w][g*4+r][c*16 + l15] = (__bf16)sv[c][r];
    }
    asm volatile("s_waitcnt lgkmcnt(0)" ::: "memory");
    __builtin_amdgcn_sched_barrier(0);
    bf16x8 pa0 = *reinterpret_cast<const bf16x8*>(&Plds[w][l15][g*8]);
    bf16x8 pa1 = *reinterpret_cast<const bf16x8*>(&Plds[w][l15][g*8 + 32]);

    #pragma unroll
    for (int ch=0; ch<4; ++ch){
      bf16x8 vb0 = *reinterpret_cast<const bf16x8*>(&Vlds[ch*16 + l15][g*8]);
      bf16x8 vb1 = *reinterpret_cast<const bf16x8*>(&Vlds[ch*16 + l15][g*8 + 32]);
      o[ch] = mfma16(pa0, vb0, o[ch]);
      o[ch] = mfma16(pa1, vb1, o[ch]);
    }
  }

  // one cross-lane reduce of l at the end
  float lr[4];
  #pragma unroll
  for (int r=0;r<4;r++){
    float v = lp[r];
    v += __shfl_xor(v, 1);
    v += __shfl_xor(v, 2);
    v += __shfl_xor(v, 4);
    v += __shfl_xor(v, 8);
    lr[r] = v;
  }
  float rl[4];
  #pragma unroll
  for (int r=0;r<4;r++) rl[r] = (lr[r] > 0.0f) ? 1.0f/lr[r] : 0.0f;

  __bf16* podst = po + (size_t)pidx*4096;
  #pragma unroll
  for (int ch=0; ch<4; ++ch){
    #pragma unroll
    for (int r=0;r<4;r++)
      podst[(w*16 + g*4 + r)*64 + ch*16 + l15] = (__bf16)(o[ch][r] * rl[r]);
  }
  if (l15 == 0){
    #pragma unroll
    for (int r=0;r<4;r++) pl[pidx*64 + w*16 + g*4 + r] = lr[r];
  }
}

// ---------- kernel 4: combine partials (common fixed max -> weights are just l).
template<int NS>
__global__ __launch_bounds__(256) void comb_k(const __bf16* __restrict__ po,
    const float* __restrict__ pl, float* __restrict__ out){
  const int idx   = blockIdx.x*256 + threadIdx.x;
  const int qrow  = idx >> 6;
  const int dim   = idx & 63;
  const int qtg   = qrow >> 6;
  const int rowin = qrow & 63;

  float num = 0.0f, den = 0.0f;
  #pragma unroll
  for (int s=0;s<NS;s++){
    const float l = pl[(qtg*NS + s)*64 + rowin];
    den += l;
    num += l * (float)po[(size_t)(qtg*NS + s)*4096 + rowin*64 + dim];
  }
  out[idx] = num / den;
}

extern "C" void kernel_launch(void* const* d_in, const int* in_sizes, int n_in,
                              void* d_out, int out_size, void* d_ws, size_t ws_size,
                              hipStream_t stream) {
  const float* x  = (const float*)d_in[0];
  const float* Wk = (const float*)d_in[2];
  const float* Wq = (const float*)d_in[3];
  const float* Wv = (const float*)d_in[4];
  float* out = (float*)d_out;

  char* ws = (char*)d_ws;
  __bf16* Wbf = (__bf16*)ws;                         // 384 KiB
  __bf16* kb  = (__bf16*)(ws + 393216);              // 2 MiB
  __bf16* qb  = (__bf16*)(ws + 2490368);             // 2 MiB
  __bf16* vTb = (__bf16*)(ws + 4587520);             // 2 MiB
  __bf16* po  = (__bf16*)(ws + 6684672);

  wconv_k<<<192, 256, 0, stream>>>(Wk, Wq, Wv, Wbf);
  proj_k <<<256, 512, 0, stream>>>(x, Wbf, kb, qb, vTb);

  const size_t need8 = 6684672ull + (size_t)2048*4096*2 + (size_t)2048*64*4;
  if (ws_size >= need8){
    float* pl = (float*)(ws + 6684672 + (size_t)2048*4096*2);
    attn_part_k<8><<<2048, 256, 0, stream>>>(kb, qb, vTb, po, pl);
    comb_k<8>    <<<4096, 256, 0, stream>>>(po, pl, out);
  } else {
    float* pl = (float*)(ws + 6684672 + (size_t)1024*4096*2);
    attn_part_k<4><<<1024, 256, 0, stream>>>(kb, qb, vTb, po, pl);
    comb_k<4>    <<<4096, 256, 0, stream>>>(po, pl, out);
  }
}

// Round 5
// 97.044 us; speedup vs baseline: 1.6109x; 1.0717x over previous
//
#include <hip/hip_runtime.h>
#include <hip/hip_bf16.h>

#define BT 16384      // B*T rows
#define CDIM 1024
#define HD 64
#define TT 4096

typedef __bf16 bf16x8 __attribute__((ext_vector_type(8)));
typedef __bf16 bf16x4 __attribute__((ext_vector_type(4)));
typedef float f32x4 __attribute__((ext_vector_type(4)));

__device__ __forceinline__ f32x4 mfma16(bf16x8 a, bf16x8 b, f32x4 c){
  return __builtin_amdgcn_mfma_f32_16x16x32_bf16(a, b, c, 0, 0, 0);
}

// ---------- kernel 1: weights -> bf16 [192][1024]; rows 64..127 (Wq) pre-scaled by 1/8
__global__ __launch_bounds__(256) void wconv_k(const float* __restrict__ Wk,
    const float* __restrict__ Wq, const float* __restrict__ Wv,
    __bf16* __restrict__ Wbf){
  int idx = blockIdx.x*256 + threadIdx.x;
  int e0 = idx*4;
  int n = e0 >> 10;
  int c = e0 & 1023;
  const float* src; float s;
  if (n < 64)      { src = Wk + (size_t)n*CDIM;       s = 1.0f;   }
  else if (n < 128){ src = Wq + (size_t)(n-64)*CDIM;  s = 0.125f; }
  else             { src = Wv + (size_t)(n-128)*CDIM; s = 1.0f;   }
  float4 v = *reinterpret_cast<const float4*>(src + c);
  __bf16* dst = Wbf + e0;
  dst[0]=(__bf16)(v.x*s); dst[1]=(__bf16)(v.y*s);
  dst[2]=(__bf16)(v.z*s); dst[3]=(__bf16)(v.w*s);
}

// ---------- kernel 2: projections, K-split x4 within block.
// grid 1024 x 256 thr (4 waves). Block owns 16 rows; wave w does K-quarter [w*256,(w+1)*256).
// Waves 0-2 deposit f32 partials in LDS; wave 3 combines and stores
// k,q row-major [BT][64] and v transposed [B][64][T].
__global__ __launch_bounds__(256) void proj_k(const float* __restrict__ x,
    const __bf16* __restrict__ Wbf, __bf16* __restrict__ kb,
    __bf16* __restrict__ qb, __bf16* __restrict__ vTb){
  __shared__ float redbuf[3][16][196];

  const int tid  = threadIdx.x;
  const int lane = tid & 63;
  const int w    = tid >> 6;        // K-quarter 0..3
  const int l15  = lane & 15, g = lane >> 4;
  const long row0  = (long)blockIdx.x*16;
  const int  kbase = w*256;

  f32x4 acc[12];
  #pragma unroll
  for (int j=0;j<12;j++) acc[j] = (f32x4)(0.0f);

  const float* xrow = x + (row0 + l15)*CDIM + kbase;

  // prefetch depth 2 over 8 K-steps
  float4 alo = *reinterpret_cast<const float4*>(xrow + g*8);
  float4 ahi = *reinterpret_cast<const float4*>(xrow + g*8 + 4);
  float4 blo = *reinterpret_cast<const float4*>(xrow + 32 + g*8);
  float4 bhi = *reinterpret_cast<const float4*>(xrow + 32 + g*8 + 4);

  for (int it=0; it<8; ++it){
    const int nk = (it+2 < 8) ? (it+2)*32 : it*32;
    float4 nlo = *reinterpret_cast<const float4*>(xrow + nk + g*8);
    float4 nhi = *reinterpret_cast<const float4*>(xrow + nk + g*8 + 4);

    bf16x8 a;
    a[0]=(__bf16)alo.x; a[1]=(__bf16)alo.y; a[2]=(__bf16)alo.z; a[3]=(__bf16)alo.w;
    a[4]=(__bf16)ahi.x; a[5]=(__bf16)ahi.y; a[6]=(__bf16)ahi.z; a[7]=(__bf16)ahi.w;

    const int kk0 = kbase + it*32 + g*8;
    #pragma unroll
    for (int nc=0; nc<12; ++nc){
      bf16x8 b = *reinterpret_cast<const bf16x8*>(Wbf + (size_t)(nc*16 + l15)*CDIM + kk0);
      acc[nc] = mfma16(a, b, acc[nc]);
    }
    alo = blo; ahi = bhi; blo = nlo; bhi = nhi;
  }

  // K-reduction: waves 0-2 deposit, wave 3 combines + stores
  if (w < 3){
    #pragma unroll
    for (int nc=0; nc<12; ++nc){
      #pragma unroll
      for (int r=0;r<4;r++)
        redbuf[w][g*4 + r][nc*16 + l15] = acc[nc][r];
    }
  }
  __syncthreads();
  if (w == 3){
    const long rr0 = row0 + g*4;
    #pragma unroll
    for (int nc=0; nc<12; ++nc){
      const int mat = nc >> 2;              // 0=k, 1=q, 2=v
      const int h   = (nc & 3)*16 + l15;
      float sum[4];
      #pragma unroll
      for (int r=0;r<4;r++)
        sum[r] = acc[nc][r] + redbuf[0][g*4+r][nc*16+l15]
                            + redbuf[1][g*4+r][nc*16+l15]
                            + redbuf[2][g*4+r][nc*16+l15];
      if (mat == 0){
        __bf16* dst = kb + rr0*HD + h;
        #pragma unroll
        for (int r=0;r<4;r++) dst[r*HD] = (__bf16)sum[r];
      } else if (mat == 1){
        __bf16* dst = qb + rr0*HD + h;
        #pragma unroll
        for (int r=0;r<4;r++) dst[r*HD] = (__bf16)sum[r];
      } else {
        const long bidx = rr0 >> 12;
        const long t0   = rr0 & 4095;
        bf16x4 t4;
        #pragma unroll
        for (int r=0;r<4;r++) t4[r] = (__bf16)sum[r];
        *reinterpret_cast<bf16x4*>(vTb + (bidx*64 + h)*TT + t0) = t4;
      }
    }
  }
}

// ---------- kernel 3: causal flash attention, fixed-max softmax, KV-split partials.
// grid = B * 64 qtiles * NS, 256 thr (4 waves x 16 q-rows). p = exp(s - 16), no max/rescale.
template<int NS>
__global__ __launch_bounds__(256) void attn_part_k(const __bf16* __restrict__ kbg,
    const __bf16* __restrict__ qbg, const __bf16* __restrict__ vT,
    __bf16* __restrict__ po, float* __restrict__ pl){
  __shared__ __bf16 Klds[64][68];     // [key][dim]
  __shared__ __bf16 Vlds[64][68];     // [dim][key]  (from pre-transposed vT)
  __shared__ __bf16 Plds[4][16][68];  // per-wave P round-trip

  const int tid  = threadIdx.x;
  const int lane = tid & 63;
  const int w    = tid >> 6;
  const int l15  = lane & 15, g = lane >> 4;

  const int bi  = blockIdx.x;
  const int b   = bi / (64*NS);
  const int rem = bi % (64*NS);
  const int qt  = 63 - rem / NS;      // longest blocks dispatch first
  const int s   = rem % NS;

  const int ntiles = qt + 1;
  const int lo = ( s      * ntiles) / NS;
  const int hi = ((s + 1) * ntiles) / NS;
  const int pidx = (b*64 + qt)*NS + s;

  if (lo == hi){                      // empty split (block-uniform): weight 0
    if (l15 == 0){
      #pragma unroll
      for (int r=0;r<4;r++) pl[pidx*64 + w*16 + g*4 + r] = 0.0f;
    }
    return;
  }

  const long qbase = (long)b*TT + (long)qt*64;

  bf16x8 qf0, qf1;
  {
    const __bf16* src = qbg + (qbase + w*16 + l15)*HD + g*8;
    qf0 = *reinterpret_cast<const bf16x8*>(src);
    qf1 = *reinterpret_cast<const bf16x8*>(src + 32);
  }

  f32x4 o[4];
  #pragma unroll
  for (int ch=0; ch<4; ++ch) o[ch] = (f32x4)(0.0f);
  float lp[4] = {0.f, 0.f, 0.f, 0.f};

  const __bf16* vbase = vT + (size_t)b*64*TT;

  for (int kv=lo; kv<hi; ++kv){
    const long kvbase = (long)b*TT + (long)kv*64;
    const int  kvt    = kv*64;

    __syncthreads();                  // previous tile fully consumed
    {
      const int key = tid >> 2;
      const int d0  = (tid & 3) * 16;
      const __bf16* ks = kbg + (kvbase + key)*HD + d0;
      *reinterpret_cast<bf16x8*>(&Klds[key][d0])   = *reinterpret_cast<const bf16x8*>(ks);
      *reinterpret_cast<bf16x8*>(&Klds[key][d0+8]) = *reinterpret_cast<const bf16x8*>(ks+8);
      const int h    = tid >> 2;
      const int key0 = (tid & 3) * 16;
      const __bf16* vs = vbase + (size_t)h*TT + kvt + key0;
      *reinterpret_cast<bf16x8*>(&Vlds[h][key0])   = *reinterpret_cast<const bf16x8*>(vs);
      *reinterpret_cast<bf16x8*>(&Vlds[h][key0+8]) = *reinterpret_cast<const bf16x8*>(vs+8);
    }
    __syncthreads();

    // S - 16 = Q K^T - 16 (seed accumulator with -16)
    f32x4 sv[4];
    #pragma unroll
    for (int c=0;c<4;c++){
      bf16x8 kb0 = *reinterpret_cast<const bf16x8*>(&Klds[c*16 + l15][g*8]);
      bf16x8 kb1 = *reinterpret_cast<const bf16x8*>(&Klds[c*16 + l15][g*8 + 32]);
      sv[c] = mfma16(qf0, kb0, (f32x4)(-16.0f));
      sv[c] = mfma16(qf1, kb1, sv[c]);
    }

    if (kv == qt){   // diagonal tile: causal mask
      #pragma unroll
      for (int c=0;c<4;c++){
        const int key = c*16 + l15;
        #pragma unroll
        for (int r=0;r<4;r++){
          const int qr = w*16 + g*4 + r;
          if (key > qr) sv[c][r] = -1e30f;
        }
      }
    }

    // p = exp(s-16); accumulate per-lane row sums (reduced once at end)
    #pragma unroll
    for (int c=0;c<4;c++){
      #pragma unroll
      for (int r=0;r<4;r++) sv[c][r] = __expf(sv[c][r]);
    }
    #pragma unroll
    for (int r=0;r<4;r++)
      lp[r] += (sv[0][r] + sv[1][r]) + (sv[2][r] + sv[3][r]);

    // P -> per-wave LDS (C-layout) -> A-frags (wave-synchronous)
    #pragma unroll
    for (int c=0;c<4;c++){
      #pragma unroll
      for (int r=0;r<4;r++) Plds[w][g*4+r][c*16 + l15] = (__bf16)sv[c][r];
    }
    asm volatile("s_waitcnt lgkmcnt(0)" ::: "memory");
    __builtin_amdgcn_sched_barrier(0);
    bf16x8 pa0 = *reinterpret_cast<const bf16x8*>(&Plds[w][l15][g*8]);
    bf16x8 pa1 = *reinterpret_cast<const bf16x8*>(&Plds[w][l15][g*8 + 32]);

    #pragma unroll
    for (int ch=0; ch<4; ++ch){
      bf16x8 vb0 = *reinterpret_cast<const bf16x8*>(&Vlds[ch*16 + l15][g*8]);
      bf16x8 vb1 = *reinterpret_cast<const bf16x8*>(&Vlds[ch*16 + l15][g*8 + 32]);
      o[ch] = mfma16(pa0, vb0, o[ch]);
      o[ch] = mfma16(pa1, vb1, o[ch]);
    }
  }

  // one cross-lane reduce of l at the end
  float lr[4];
  #pragma unroll
  for (int r=0;r<4;r++){
    float v = lp[r];
    v += __shfl_xor(v, 1);
    v += __shfl_xor(v, 2);
    v += __shfl_xor(v, 4);
    v += __shfl_xor(v, 8);
    lr[r] = v;
  }
  float rl[4];
  #pragma unroll
  for (int r=0;r<4;r++) rl[r] = (lr[r] > 0.0f) ? 1.0f/lr[r] : 0.0f;

  __bf16* podst = po + (size_t)pidx*4096;
  #pragma unroll
  for (int ch=0; ch<4; ++ch){
    #pragma unroll
    for (int r=0;r<4;r++)
      podst[(w*16 + g*4 + r)*64 + ch*16 + l15] = (__bf16)(o[ch][r] * rl[r]);
  }
  if (l15 == 0){
    #pragma unroll
    for (int r=0;r<4;r++) pl[pidx*64 + w*16 + g*4 + r] = lr[r];
  }
}

// ---------- kernel 4: combine partials (common fixed max -> weights are just l).
template<int NS>
__global__ __launch_bounds__(256) void comb_k(const __bf16* __restrict__ po,
    const float* __restrict__ pl, float* __restrict__ out){
  const int idx   = blockIdx.x*256 + threadIdx.x;
  const int qrow  = idx >> 6;
  const int dim   = idx & 63;
  const int qtg   = qrow >> 6;
  const int rowin = qrow & 63;

  float num = 0.0f, den = 0.0f;
  #pragma unroll
  for (int s=0;s<NS;s++){
    const float l = pl[(qtg*NS + s)*64 + rowin];
    den += l;
    num += l * (float)po[(size_t)(qtg*NS + s)*4096 + rowin*64 + dim];
  }
  out[idx] = num / den;
}

extern "C" void kernel_launch(void* const* d_in, const int* in_sizes, int n_in,
                              void* d_out, int out_size, void* d_ws, size_t ws_size,
                              hipStream_t stream) {
  const float* x  = (const float*)d_in[0];
  const float* Wk = (const float*)d_in[2];
  const float* Wq = (const float*)d_in[3];
  const float* Wv = (const float*)d_in[4];
  float* out = (float*)d_out;

  char* ws = (char*)d_ws;
  __bf16* Wbf = (__bf16*)ws;                         // 384 KiB
  __bf16* kb  = (__bf16*)(ws + 393216);              // 2 MiB
  __bf16* qb  = (__bf16*)(ws + 2490368);             // 2 MiB
  __bf16* vTb = (__bf16*)(ws + 4587520);             // 2 MiB
  __bf16* po  = (__bf16*)(ws + 6684672);

  wconv_k<<<192,  256, 0, stream>>>(Wk, Wq, Wv, Wbf);
  proj_k <<<1024, 256, 0, stream>>>(x, Wbf, kb, qb, vTb);

  const size_t need8 = 6684672ull + (size_t)2048*4096*2 + (size_t)2048*64*4;
  if (ws_size >= need8){
    float* pl = (float*)(ws + 6684672 + (size_t)2048*4096*2);
    attn_part_k<8><<<2048, 256, 0, stream>>>(kb, qb, vTb, po, pl);
    comb_k<8>    <<<4096, 256, 0, stream>>>(po, pl, out);
  } else {
    float* pl = (float*)(ws + 6684672 + (size_t)1024*4096*2);
    attn_part_k<4><<<1024, 256, 0, stream>>>(kb, qb, vTb, po, pl);
    comb_k<4>    <<<4096, 256, 0, stream>>>(po, pl, out);
  }
}

// Round 6
// 65.262 us; speedup vs baseline: 2.3954x; 1.4870x over previous
//
#include <hip/hip_runtime.h>
#include <hip/hip_bf16.h>

#define BT 16384      // B*T rows
#define CDIM 1024
#define HD 64
#define TT 4096

typedef __bf16 bf16x8 __attribute__((ext_vector_type(8)));
typedef __bf16 bf16x4 __attribute__((ext_vector_type(4)));
typedef float f32x4 __attribute__((ext_vector_type(4)));

__device__ __forceinline__ f32x4 mfma16(bf16x8 a, bf16x8 b, f32x4 c){
  return __builtin_amdgcn_mfma_f32_16x16x32_bf16(a, b, c, 0, 0, 0);
}

// ---------- kernel 1: weights -> bf16 [192][1024]; rows 64..127 (Wq) pre-scaled by 1/8
__global__ __launch_bounds__(256) void wconv_k(const float* __restrict__ Wk,
    const float* __restrict__ Wq, const float* __restrict__ Wv,
    __bf16* __restrict__ Wbf){
  int idx = blockIdx.x*256 + threadIdx.x;
  int e0 = idx*4;
  int n = e0 >> 10;
  int c = e0 & 1023;
  const float* src; float s;
  if (n < 64)      { src = Wk + (size_t)n*CDIM;       s = 1.0f;   }
  else if (n < 128){ src = Wq + (size_t)(n-64)*CDIM;  s = 0.125f; }
  else             { src = Wv + (size_t)(n-128)*CDIM; s = 1.0f;   }
  float4 v = *reinterpret_cast<const float4*>(src + c);
  __bf16* dst = Wbf + e0;
  dst[0]=(__bf16)(v.x*s); dst[1]=(__bf16)(v.y*s);
  dst[2]=(__bf16)(v.z*s); dst[3]=(__bf16)(v.w*s);
}

// ---------- kernel 2: projections as LDS-staged tiled GEMM.
// grid 256 x 512 thr (8 waves). Block: 64 rows x 192 outputs, K=1024 in 16 steps of 64.
// Per step: stage Wt[192][64] + Xt[64][64] (f32->bf16) into LDS, 2-barrier, MFMA from LDS.
// Wave (wr,wn): rows wr*32..+31 (2 frags), cols wn*48..+47 (3 frags).
__global__ __launch_bounds__(512) void proj_k(const float* __restrict__ x,
    const __bf16* __restrict__ Wbf, __bf16* __restrict__ kb,
    __bf16* __restrict__ qb, __bf16* __restrict__ vTb){
  __shared__ __bf16 Wt[192][72];    // 27.6 KB
  __shared__ __bf16 Xt[64][72];     //  9.2 KB

  const int tid  = threadIdx.x;
  const int lane = tid & 63;
  const int w    = tid >> 6;        // 0..7
  const int wr   = w >> 2;          // row half
  const int wn   = w & 3;           // N quarter
  const int l15  = lane & 15, g = lane >> 4;
  const long row0 = (long)blockIdx.x*64;

  f32x4 acc[2][3];
  #pragma unroll
  for (int a=0;a<2;a++)
    #pragma unroll
    for (int b=0;b<3;b++) acc[a][b] = (f32x4)(0.0f);

  for (int kk=0; kk<16; ++kk){
    const int kk0 = kk*64;
    __syncthreads();                       // prev step's LDS fully consumed
    // stage W tile: 192x64 bf16 = 1536 chunks of 8; 3 per thread
    #pragma unroll
    for (int i=0;i<3;i++){
      const int c  = tid + 512*i;
      const int rw = c >> 3, c8 = (c & 7)*8;
      bf16x8 wv = *reinterpret_cast<const bf16x8*>(Wbf + (size_t)rw*CDIM + kk0 + c8);
      *reinterpret_cast<bf16x8*>(&Wt[rw][c8]) = wv;
    }
    // stage X tile: 64x64, f32 -> bf16; 1 chunk per thread
    {
      const int rw = tid >> 3, c8 = (tid & 7)*8;
      const float* src = x + (row0 + rw)*CDIM + kk0 + c8;
      float4 lo = *reinterpret_cast<const float4*>(src);
      float4 hi = *reinterpret_cast<const float4*>(src + 4);
      bf16x8 xv;
      xv[0]=(__bf16)lo.x; xv[1]=(__bf16)lo.y; xv[2]=(__bf16)lo.z; xv[3]=(__bf16)lo.w;
      xv[4]=(__bf16)hi.x; xv[5]=(__bf16)hi.y; xv[6]=(__bf16)hi.z; xv[7]=(__bf16)hi.w;
      *reinterpret_cast<bf16x8*>(&Xt[rw][c8]) = xv;
    }
    __syncthreads();

    bf16x8 a0[2], a1[2], b0[3], b1[3];
    #pragma unroll
    for (int rf=0;rf<2;rf++){
      a0[rf] = *reinterpret_cast<const bf16x8*>(&Xt[wr*32 + rf*16 + l15][g*8]);
      a1[rf] = *reinterpret_cast<const bf16x8*>(&Xt[wr*32 + rf*16 + l15][g*8 + 32]);
    }
    #pragma unroll
    for (int nf=0;nf<3;nf++){
      b0[nf] = *reinterpret_cast<const bf16x8*>(&Wt[wn*48 + nf*16 + l15][g*8]);
      b1[nf] = *reinterpret_cast<const bf16x8*>(&Wt[wn*48 + nf*16 + l15][g*8 + 32]);
    }
    #pragma unroll
    for (int rf=0;rf<2;rf++)
      #pragma unroll
      for (int nf=0;nf<3;nf++)
        acc[rf][nf] = mfma16(a1[rf], b1[nf], mfma16(a0[rf], b0[nf], acc[rf][nf]));
  }

  // epilogue: k,q row-major [BT][64]; v transposed [B][64][T]
  const long bidx = row0 >> 12;            // batch (block never crosses batch)
  #pragma unroll
  for (int nf=0;nf<3;nf++){
    const int n0  = wn*48 + nf*16 + l15;
    const int mat = n0 >> 6;               // 0=k, 1=q, 2=v
    const int h   = n0 & 63;
    #pragma unroll
    for (int rf=0;rf<2;rf++){
      const long rbase = row0 + wr*32 + rf*16 + g*4;
      if (mat == 0){
        #pragma unroll
        for (int r=0;r<4;r++) kb[(rbase+r)*HD + h] = (__bf16)acc[rf][nf][r];
      } else if (mat == 1){
        #pragma unroll
        for (int r=0;r<4;r++) qb[(rbase+r)*HD + h] = (__bf16)acc[rf][nf][r];
      } else {
        bf16x4 t4;
        #pragma unroll
        for (int r=0;r<4;r++) t4[r] = (__bf16)acc[rf][nf][r];
        *reinterpret_cast<bf16x4*>(vTb + (bidx*64 + h)*TT + (rbase & 4095)) = t4;
      }
    }
  }
}

// ---------- kernel 3: causal flash attention, fixed-max softmax, KV-split partials.
// grid = B * 64 qtiles * NS, 256 thr (4 waves x 16 q-rows). p = exp(s - 16), no max/rescale.
template<int NS>
__global__ __launch_bounds__(256) void attn_part_k(const __bf16* __restrict__ kbg,
    const __bf16* __restrict__ qbg, const __bf16* __restrict__ vT,
    __bf16* __restrict__ po, float* __restrict__ pl){
  __shared__ __bf16 Klds[64][68];     // [key][dim]
  __shared__ __bf16 Vlds[64][68];     // [dim][key]  (from pre-transposed vT)
  __shared__ __bf16 Plds[4][16][68];  // per-wave P round-trip

  const int tid  = threadIdx.x;
  const int lane = tid & 63;
  const int w    = tid >> 6;
  const int l15  = lane & 15, g = lane >> 4;

  const int bi  = blockIdx.x;
  const int b   = bi / (64*NS);
  const int rem = bi % (64*NS);
  const int qt  = 63 - rem / NS;      // longest blocks dispatch first
  const int s   = rem % NS;

  const int ntiles = qt + 1;
  const int lo = ( s      * ntiles) / NS;
  const int hi = ((s + 1) * ntiles) / NS;
  const int pidx = (b*64 + qt)*NS + s;

  if (lo == hi){                      // empty split (block-uniform): weight 0
    if (l15 == 0){
      #pragma unroll
      for (int r=0;r<4;r++) pl[pidx*64 + w*16 + g*4 + r] = 0.0f;
    }
    return;
  }

  const long qbase = (long)b*TT + (long)qt*64;

  bf16x8 qf0, qf1;
  {
    const __bf16* src = qbg + (qbase + w*16 + l15)*HD + g*8;
    qf0 = *reinterpret_cast<const bf16x8*>(src);
    qf1 = *reinterpret_cast<const bf16x8*>(src + 32);
  }

  f32x4 o[4];
  #pragma unroll
  for (int ch=0; ch<4; ++ch) o[ch] = (f32x4)(0.0f);
  float lp[4] = {0.f, 0.f, 0.f, 0.f};

  const __bf16* vbase = vT + (size_t)b*64*TT;

  for (int kv=lo; kv<hi; ++kv){
    const long kvbase = (long)b*TT + (long)kv*64;
    const int  kvt    = kv*64;

    __syncthreads();                  // previous tile fully consumed
    {
      const int key = tid >> 2;
      const int d0  = (tid & 3) * 16;
      const __bf16* ks = kbg + (kvbase + key)*HD + d0;
      *reinterpret_cast<bf16x8*>(&Klds[key][d0])   = *reinterpret_cast<const bf16x8*>(ks);
      *reinterpret_cast<bf16x8*>(&Klds[key][d0+8]) = *reinterpret_cast<const bf16x8*>(ks+8);
      const int h    = tid >> 2;
      const int key0 = (tid & 3) * 16;
      const __bf16* vs = vbase + (size_t)h*TT + kvt + key0;
      *reinterpret_cast<bf16x8*>(&Vlds[h][key0])   = *reinterpret_cast<const bf16x8*>(vs);
      *reinterpret_cast<bf16x8*>(&Vlds[h][key0+8]) = *reinterpret_cast<const bf16x8*>(vs+8);
    }
    __syncthreads();

    // S - 16 = Q K^T - 16 (seed accumulator with -16)
    f32x4 sv[4];
    #pragma unroll
    for (int c=0;c<4;c++){
      bf16x8 kb0 = *reinterpret_cast<const bf16x8*>(&Klds[c*16 + l15][g*8]);
      bf16x8 kb1 = *reinterpret_cast<const bf16x8*>(&Klds[c*16 + l15][g*8 + 32]);
      sv[c] = mfma16(qf0, kb0, (f32x4)(-16.0f));
      sv[c] = mfma16(qf1, kb1, sv[c]);
    }

    if (kv == qt){   // diagonal tile: causal mask
      #pragma unroll
      for (int c=0;c<4;c++){
        const int key = c*16 + l15;
        #pragma unroll
        for (int r=0;r<4;r++){
          const int qr = w*16 + g*4 + r;
          if (key > qr) sv[c][r] = -1e30f;
        }
      }
    }

    // p = exp(s-16); accumulate per-lane row sums (reduced once at end)
    #pragma unroll
    for (int c=0;c<4;c++){
      #pragma unroll
      for (int r=0;r<4;r++) sv[c][r] = __expf(sv[c][r]);
    }
    #pragma unroll
    for (int r=0;r<4;r++)
      lp[r] += (sv[0][r] + sv[1][r]) + (sv[2][r] + sv[3][r]);

    // P -> per-wave LDS (C-layout) -> A-frags (wave-synchronous)
    #pragma unroll
    for (int c=0;c<4;c++){
      #pragma unroll
      for (int r=0;r<4;r++) Plds[w][g*4+r][c*16 + l15] = (__bf16)sv[c][r];
    }
    asm volatile("s_waitcnt lgkmcnt(0)" ::: "memory");
    __builtin_amdgcn_sched_barrier(0);
    bf16x8 pa0 = *reinterpret_cast<const bf16x8*>(&Plds[w][l15][g*8]);
    bf16x8 pa1 = *reinterpret_cast<const bf16x8*>(&Plds[w][l15][g*8 + 32]);

    #pragma unroll
    for (int ch=0; ch<4; ++ch){
      bf16x8 vb0 = *reinterpret_cast<const bf16x8*>(&Vlds[ch*16 + l15][g*8]);
      bf16x8 vb1 = *reinterpret_cast<const bf16x8*>(&Vlds[ch*16 + l15][g*8 + 32]);
      o[ch] = mfma16(pa0, vb0, o[ch]);
      o[ch] = mfma16(pa1, vb1, o[ch]);
    }
  }

  // one cross-lane reduce of l at the end
  float lr[4];
  #pragma unroll
  for (int r=0;r<4;r++){
    float v = lp[r];
    v += __shfl_xor(v, 1);
    v += __shfl_xor(v, 2);
    v += __shfl_xor(v, 4);
    v += __shfl_xor(v, 8);
    lr[r] = v;
  }
  float rl[4];
  #pragma unroll
  for (int r=0;r<4;r++) rl[r] = (lr[r] > 0.0f) ? 1.0f/lr[r] : 0.0f;

  __bf16* podst = po + (size_t)pidx*4096;
  #pragma unroll
  for (int ch=0; ch<4; ++ch){
    #pragma unroll
    for (int r=0;r<4;r++)
      podst[(w*16 + g*4 + r)*64 + ch*16 + l15] = (__bf16)(o[ch][r] * rl[r]);
  }
  if (l15 == 0){
    #pragma unroll
    for (int r=0;r<4;r++) pl[pidx*64 + w*16 + g*4 + r] = lr[r];
  }
}

// ---------- kernel 4: combine partials (common fixed max -> weights are just l).
template<int NS>
__global__ __launch_bounds__(256) void comb_k(const __bf16* __restrict__ po,
    const float* __restrict__ pl, float* __restrict__ out){
  const int idx   = blockIdx.x*256 + threadIdx.x;
  const int qrow  = idx >> 6;
  const int dim   = idx & 63;
  const int qtg   = qrow >> 6;
  const int rowin = qrow & 63;

  float num = 0.0f, den = 0.0f;
  #pragma unroll
  for (int s=0;s<NS;s++){
    const float l = pl[(qtg*NS + s)*64 + rowin];
    den += l;
    num += l * (float)po[(size_t)(qtg*NS + s)*4096 + rowin*64 + dim];
  }
  out[idx] = num / den;
}

extern "C" void kernel_launch(void* const* d_in, const int* in_sizes, int n_in,
                              void* d_out, int out_size, void* d_ws, size_t ws_size,
                              hipStream_t stream) {
  const float* x  = (const float*)d_in[0];
  const float* Wk = (const float*)d_in[2];
  const float* Wq = (const float*)d_in[3];
  const float* Wv = (const float*)d_in[4];
  float* out = (float*)d_out;

  char* ws = (char*)d_ws;
  __bf16* Wbf = (__bf16*)ws;                         // 384 KiB
  __bf16* kb  = (__bf16*)(ws + 393216);              // 2 MiB
  __bf16* qb  = (__bf16*)(ws + 2490368);             // 2 MiB
  __bf16* vTb = (__bf16*)(ws + 4587520);             // 2 MiB
  __bf16* po  = (__bf16*)(ws + 6684672);

  wconv_k<<<192, 256, 0, stream>>>(Wk, Wq, Wv, Wbf);
  proj_k <<<256, 512, 0, stream>>>(x, Wbf, kb, qb, vTb);

  const size_t need8 = 6684672ull + (size_t)2048*4096*2 + (size_t)2048*64*4;
  if (ws_size >= need8){
    float* pl = (float*)(ws + 6684672 + (size_t)2048*4096*2);
    attn_part_k<8><<<2048, 256, 0, stream>>>(kb, qb, vTb, po, pl);
    comb_k<8>    <<<4096, 256, 0, stream>>>(po, pl, out);
  } else {
    float* pl = (float*)(ws + 6684672 + (size_t)1024*4096*2);
    attn_part_k<4><<<1024, 256, 0, stream>>>(kb, qb, vTb, po, pl);
    comb_k<4>    <<<4096, 256, 0, stream>>>(po, pl, out);
  }
}

// Round 7
// 63.710 us; speedup vs baseline: 2.4537x; 1.0244x over previous
//
#include <hip/hip_runtime.h>
#include <hip/hip_bf16.h>

#define BT 16384      // B*T rows
#define CDIM 1024
#define HD 64
#define TT 4096

typedef __bf16 bf16x8 __attribute__((ext_vector_type(8)));
typedef __bf16 bf16x4 __attribute__((ext_vector_type(4)));
typedef float f32x4 __attribute__((ext_vector_type(4)));

__device__ __forceinline__ f32x4 mfma16(bf16x8 a, bf16x8 b, f32x4 c){
  return __builtin_amdgcn_mfma_f32_16x16x32_bf16(a, b, c, 0, 0, 0);
}

// ---------- kernel 1: weights -> bf16 [192][1024]; rows 64..127 (Wq) pre-scaled by 1/8
__global__ __launch_bounds__(256) void wconv_k(const float* __restrict__ Wk,
    const float* __restrict__ Wq, const float* __restrict__ Wv,
    __bf16* __restrict__ Wbf){
  int idx = blockIdx.x*256 + threadIdx.x;
  int e0 = idx*4;
  int n = e0 >> 10;
  int c = e0 & 1023;
  const float* src; float s;
  if (n < 64)      { src = Wk + (size_t)n*CDIM;       s = 1.0f;   }
  else if (n < 128){ src = Wq + (size_t)(n-64)*CDIM;  s = 0.125f; }
  else             { src = Wv + (size_t)(n-128)*CDIM; s = 1.0f;   }
  float4 v = *reinterpret_cast<const float4*>(src + c);
  __bf16* dst = Wbf + e0;
  dst[0]=(__bf16)(v.x*s); dst[1]=(__bf16)(v.y*s);
  dst[2]=(__bf16)(v.z*s); dst[3]=(__bf16)(v.w*s);
}

// ---------- kernel 2: projections, LDS-staged tiled GEMM + register prefetch.
// grid 256 x 512 thr (8 waves). Block: 64 rows x 192 outputs, K=1024 in 16 steps of 64.
// Next step's W/X global loads issue right after the stage-barrier -> latency hides
// under current step's ds_read+MFMA.
__global__ __launch_bounds__(512) void proj_k(const float* __restrict__ x,
    const __bf16* __restrict__ Wbf, __bf16* __restrict__ kb,
    __bf16* __restrict__ qb, __bf16* __restrict__ vTb){
  __shared__ __bf16 Wt[192][72];    // 27.6 KB
  __shared__ __bf16 Xt[64][72];     //  9.2 KB

  const int tid  = threadIdx.x;
  const int lane = tid & 63;
  const int w    = tid >> 6;        // 0..7
  const int wr   = w >> 2;          // row half
  const int wn   = w & 3;           // N quarter
  const int l15  = lane & 15, g = lane >> 4;
  const long row0 = (long)blockIdx.x*64;

  // per-thread staging slots
  const int wrw[3] = { (tid)>>3, (tid+512)>>3, (tid+1024)>>3 };
  const int wc8[3] = { (tid&7)*8, (tid&7)*8, (tid&7)*8 };   // (c&7) == (tid&7) since 512%8==0
  const int xrw = tid >> 3, xc8 = (tid & 7)*8;

  f32x4 acc[2][3];
  #pragma unroll
  for (int a=0;a<2;a++)
    #pragma unroll
    for (int b=0;b<3;b++) acc[a][b] = (f32x4)(0.0f);

  bf16x8 wreg[3];
  float4 xlo, xhi;

  // prologue: load step 0
  #pragma unroll
  for (int i=0;i<3;i++)
    wreg[i] = *reinterpret_cast<const bf16x8*>(Wbf + (size_t)wrw[i]*CDIM + wc8[i]);
  {
    const float* src = x + (row0 + xrw)*CDIM + xc8;
    xlo = *reinterpret_cast<const float4*>(src);
    xhi = *reinterpret_cast<const float4*>(src + 4);
  }

  for (int kk=0; kk<16; ++kk){
    __syncthreads();                       // prev step's LDS fully consumed
    #pragma unroll
    for (int i=0;i<3;i++)
      *reinterpret_cast<bf16x8*>(&Wt[wrw[i]][wc8[i]]) = wreg[i];
    {
      bf16x8 xv;
      xv[0]=(__bf16)xlo.x; xv[1]=(__bf16)xlo.y; xv[2]=(__bf16)xlo.z; xv[3]=(__bf16)xlo.w;
      xv[4]=(__bf16)xhi.x; xv[5]=(__bf16)xhi.y; xv[6]=(__bf16)xhi.z; xv[7]=(__bf16)xhi.w;
      *reinterpret_cast<bf16x8*>(&Xt[xrw][xc8]) = xv;
    }
    __syncthreads();

    // issue NEXT step's global loads; latency hides under ds_read+MFMA below
    if (kk < 15){
      const int nk0 = (kk+1)*64;
      #pragma unroll
      for (int i=0;i<3;i++)
        wreg[i] = *reinterpret_cast<const bf16x8*>(Wbf + (size_t)wrw[i]*CDIM + nk0 + wc8[i]);
      const float* src = x + (row0 + xrw)*CDIM + nk0 + xc8;
      xlo = *reinterpret_cast<const float4*>(src);
      xhi = *reinterpret_cast<const float4*>(src + 4);
    }

    bf16x8 a0[2], a1[2], b0[3], b1[3];
    #pragma unroll
    for (int rf=0;rf<2;rf++){
      a0[rf] = *reinterpret_cast<const bf16x8*>(&Xt[wr*32 + rf*16 + l15][g*8]);
      a1[rf] = *reinterpret_cast<const bf16x8*>(&Xt[wr*32 + rf*16 + l15][g*8 + 32]);
    }
    #pragma unroll
    for (int nf=0;nf<3;nf++){
      b0[nf] = *reinterpret_cast<const bf16x8*>(&Wt[wn*48 + nf*16 + l15][g*8]);
      b1[nf] = *reinterpret_cast<const bf16x8*>(&Wt[wn*48 + nf*16 + l15][g*8 + 32]);
    }
    #pragma unroll
    for (int rf=0;rf<2;rf++)
      #pragma unroll
      for (int nf=0;nf<3;nf++)
        acc[rf][nf] = mfma16(a1[rf], b1[nf], mfma16(a0[rf], b0[nf], acc[rf][nf]));
  }

  // epilogue: k,q row-major [BT][64]; v transposed [B][64][T]
  const long bidx = row0 >> 12;            // batch (block never crosses batch)
  #pragma unroll
  for (int nf=0;nf<3;nf++){
    const int n0  = wn*48 + nf*16 + l15;
    const int mat = n0 >> 6;               // 0=k, 1=q, 2=v
    const int h   = n0 & 63;
    #pragma unroll
    for (int rf=0;rf<2;rf++){
      const long rbase = row0 + wr*32 + rf*16 + g*4;
      if (mat == 0){
        #pragma unroll
        for (int r=0;r<4;r++) kb[(rbase+r)*HD + h] = (__bf16)acc[rf][nf][r];
      } else if (mat == 1){
        #pragma unroll
        for (int r=0;r<4;r++) qb[(rbase+r)*HD + h] = (__bf16)acc[rf][nf][r];
      } else {
        bf16x4 t4;
        #pragma unroll
        for (int r=0;r<4;r++) t4[r] = (__bf16)acc[rf][nf][r];
        *reinterpret_cast<bf16x4*>(vTb + (bidx*64 + h)*TT + (rbase & 4095)) = t4;
      }
    }
  }
}

// ---------- kernel 3: causal flash attention, fixed-max softmax, KV-split partials,
// register-prefetched K/V staging. grid = B*64*NS, 256 thr (4 waves x 16 q-rows).
template<int NS>
__global__ __launch_bounds__(256) void attn_part_k(const __bf16* __restrict__ kbg,
    const __bf16* __restrict__ qbg, const __bf16* __restrict__ vT,
    __bf16* __restrict__ po, float* __restrict__ pl){
  __shared__ __bf16 Klds[64][68];     // [key][dim]
  __shared__ __bf16 Vlds[64][68];     // [dim][key]  (from pre-transposed vT)
  __shared__ __bf16 Plds[4][16][68];  // per-wave P round-trip

  const int tid  = threadIdx.x;
  const int lane = tid & 63;
  const int w    = tid >> 6;
  const int l15  = lane & 15, g = lane >> 4;

  const int bi  = blockIdx.x;
  const int b   = bi / (64*NS);
  const int rem = bi % (64*NS);
  const int qt  = 63 - rem / NS;      // longest blocks dispatch first
  const int s   = rem % NS;

  const int ntiles = qt + 1;
  const int lo = ( s      * ntiles) / NS;
  const int hi = ((s + 1) * ntiles) / NS;
  const int pidx = (b*64 + qt)*NS + s;

  if (lo == hi){                      // empty split (block-uniform): weight 0
    if (l15 == 0){
      #pragma unroll
      for (int r=0;r<4;r++) pl[pidx*64 + w*16 + g*4 + r] = 0.0f;
    }
    return;
  }

  const long qbase = (long)b*TT + (long)qt*64;

  bf16x8 qf0, qf1;
  {
    const __bf16* src = qbg + (qbase + w*16 + l15)*HD + g*8;
    qf0 = *reinterpret_cast<const bf16x8*>(src);
    qf1 = *reinterpret_cast<const bf16x8*>(src + 32);
  }

  f32x4 o[4];
  #pragma unroll
  for (int ch=0; ch<4; ++ch) o[ch] = (f32x4)(0.0f);
  float lp[4] = {0.f, 0.f, 0.f, 0.f};

  const __bf16* vbase = vT + (size_t)b*64*TT;

  // staging slots
  const int skey = tid >> 2;          // K row / V dim
  const int sd0  = (tid & 3) * 16;
  bf16x8 kr0, kr1, vr0, vr1;

  // prologue: load tile `lo`
  {
    const long kvbase = (long)b*TT + (long)lo*64;
    const __bf16* ks = kbg + (kvbase + skey)*HD + sd0;
    kr0 = *reinterpret_cast<const bf16x8*>(ks);
    kr1 = *reinterpret_cast<const bf16x8*>(ks+8);
    const __bf16* vs = vbase + (size_t)skey*TT + lo*64 + sd0;
    vr0 = *reinterpret_cast<const bf16x8*>(vs);
    vr1 = *reinterpret_cast<const bf16x8*>(vs+8);
  }

  for (int kv=lo; kv<hi; ++kv){
    __syncthreads();                  // previous tile fully consumed
    *reinterpret_cast<bf16x8*>(&Klds[skey][sd0])   = kr0;
    *reinterpret_cast<bf16x8*>(&Klds[skey][sd0+8]) = kr1;
    *reinterpret_cast<bf16x8*>(&Vlds[skey][sd0])   = vr0;
    *reinterpret_cast<bf16x8*>(&Vlds[skey][sd0+8]) = vr1;
    __syncthreads();

    // issue NEXT tile's loads; latency hides under QK/softmax/PV below
    if (kv+1 < hi){
      const long nbase = (long)b*TT + (long)(kv+1)*64;
      const __bf16* ks = kbg + (nbase + skey)*HD + sd0;
      kr0 = *reinterpret_cast<const bf16x8*>(ks);
      kr1 = *reinterpret_cast<const bf16x8*>(ks+8);
      const __bf16* vs = vbase + (size_t)skey*TT + (kv+1)*64 + sd0;
      vr0 = *reinterpret_cast<const bf16x8*>(vs);
      vr1 = *reinterpret_cast<const bf16x8*>(vs+8);
    }

    // S - 16 = Q K^T - 16 (seed accumulator with -16)
    f32x4 sv[4];
    #pragma unroll
    for (int c=0;c<4;c++){
      bf16x8 kb0 = *reinterpret_cast<const bf16x8*>(&Klds[c*16 + l15][g*8]);
      bf16x8 kb1 = *reinterpret_cast<const bf16x8*>(&Klds[c*16 + l15][g*8 + 32]);
      sv[c] = mfma16(qf0, kb0, (f32x4)(-16.0f));
      sv[c] = mfma16(qf1, kb1, sv[c]);
    }

    if (kv == qt){   // diagonal tile: causal mask
      #pragma unroll
      for (int c=0;c<4;c++){
        const int key = c*16 + l15;
        #pragma unroll
        for (int r=0;r<4;r++){
          const int qr = w*16 + g*4 + r;
          if (key > qr) sv[c][r] = -1e30f;
        }
      }
    }

    // p = exp(s-16); accumulate per-lane row sums (reduced once at end)
    #pragma unroll
    for (int c=0;c<4;c++){
      #pragma unroll
      for (int r=0;r<4;r++) sv[c][r] = __expf(sv[c][r]);
    }
    #pragma unroll
    for (int r=0;r<4;r++)
      lp[r] += (sv[0][r] + sv[1][r]) + (sv[2][r] + sv[3][r]);

    // P -> per-wave LDS (C-layout) -> A-frags (wave-synchronous)
    #pragma unroll
    for (int c=0;c<4;c++){
      #pragma unroll
      for (int r=0;r<4;r++) Plds[w][g*4+r][c*16 + l15] = (__bf16)sv[c][r];
    }
    asm volatile("s_waitcnt lgkmcnt(0)" ::: "memory");
    __builtin_amdgcn_sched_barrier(0);
    bf16x8 pa0 = *reinterpret_cast<const bf16x8*>(&Plds[w][l15][g*8]);
    bf16x8 pa1 = *reinterpret_cast<const bf16x8*>(&Plds[w][l15][g*8 + 32]);

    #pragma unroll
    for (int ch=0; ch<4; ++ch){
      bf16x8 vb0 = *reinterpret_cast<const bf16x8*>(&Vlds[ch*16 + l15][g*8]);
      bf16x8 vb1 = *reinterpret_cast<const bf16x8*>(&Vlds[ch*16 + l15][g*8 + 32]);
      o[ch] = mfma16(pa0, vb0, o[ch]);
      o[ch] = mfma16(pa1, vb1, o[ch]);
    }
  }

  // one cross-lane reduce of l at the end
  float lr[4];
  #pragma unroll
  for (int r=0;r<4;r++){
    float v = lp[r];
    v += __shfl_xor(v, 1);
    v += __shfl_xor(v, 2);
    v += __shfl_xor(v, 4);
    v += __shfl_xor(v, 8);
    lr[r] = v;
  }
  float rl[4];
  #pragma unroll
  for (int r=0;r<4;r++) rl[r] = (lr[r] > 0.0f) ? 1.0f/lr[r] : 0.0f;

  __bf16* podst = po + (size_t)pidx*4096;
  #pragma unroll
  for (int ch=0; ch<4; ++ch){
    #pragma unroll
    for (int r=0;r<4;r++)
      podst[(w*16 + g*4 + r)*64 + ch*16 + l15] = (__bf16)(o[ch][r] * rl[r]);
  }
  if (l15 == 0){
    #pragma unroll
    for (int r=0;r<4;r++) pl[pidx*64 + w*16 + g*4 + r] = lr[r];
  }
}

// ---------- kernel 4: combine partials (common fixed max -> weights are just l).
template<int NS>
__global__ __launch_bounds__(256) void comb_k(const __bf16* __restrict__ po,
    const float* __restrict__ pl, float* __restrict__ out){
  const int idx   = blockIdx.x*256 + threadIdx.x;
  const int qrow  = idx >> 6;
  const int dim   = idx & 63;
  const int qtg   = qrow >> 6;
  const int rowin = qrow & 63;

  float num = 0.0f, den = 0.0f;
  #pragma unroll
  for (int s=0;s<NS;s++){
    const float l = pl[(qtg*NS + s)*64 + rowin];
    den += l;
    num += l * (float)po[(size_t)(qtg*NS + s)*4096 + rowin*64 + dim];
  }
  out[idx] = num / den;
}

extern "C" void kernel_launch(void* const* d_in, const int* in_sizes, int n_in,
                              void* d_out, int out_size, void* d_ws, size_t ws_size,
                              hipStream_t stream) {
  const float* x  = (const float*)d_in[0];
  const float* Wk = (const float*)d_in[2];
  const float* Wq = (const float*)d_in[3];
  const float* Wv = (const float*)d_in[4];
  float* out = (float*)d_out;

  char* ws = (char*)d_ws;
  __bf16* Wbf = (__bf16*)ws;                         // 384 KiB
  __bf16* kb  = (__bf16*)(ws + 393216);              // 2 MiB
  __bf16* qb  = (__bf16*)(ws + 2490368);             // 2 MiB
  __bf16* vTb = (__bf16*)(ws + 4587520);             // 2 MiB
  __bf16* po  = (__bf16*)(ws + 6684672);

  wconv_k<<<192, 256, 0, stream>>>(Wk, Wq, Wv, Wbf);
  proj_k <<<256, 512, 0, stream>>>(x, Wbf, kb, qb, vTb);

  const size_t need8 = 6684672ull + (size_t)2048*4096*2 + (size_t)2048*64*4;
  if (ws_size >= need8){
    float* pl = (float*)(ws + 6684672 + (size_t)2048*4096*2);
    attn_part_k<8><<<2048, 256, 0, stream>>>(kb, qb, vTb, po, pl);
    comb_k<8>    <<<4096, 256, 0, stream>>>(po, pl, out);
  } else {
    float* pl = (float*)(ws + 6684672 + (size_t)1024*4096*2);
    attn_part_k<4><<<1024, 256, 0, stream>>>(kb, qb, vTb, po, pl);
    comb_k<4>    <<<4096, 256, 0, stream>>>(po, pl, out);
  }
}

// Round 8
// 62.844 us; speedup vs baseline: 2.4875x; 1.0138x over previous
//
#include <hip/hip_runtime.h>
#include <hip/hip_bf16.h>

#define BT 16384      // B*T rows
#define CDIM 1024
#define HD 64
#define TT 4096

typedef __bf16 bf16x8 __attribute__((ext_vector_type(8)));
typedef __bf16 bf16x4 __attribute__((ext_vector_type(4)));
typedef float f32x4 __attribute__((ext_vector_type(4)));

__device__ __forceinline__ f32x4 mfma16(bf16x8 a, bf16x8 b, f32x4 c){
  return __builtin_amdgcn_mfma_f32_16x16x32_bf16(a, b, c, 0, 0, 0);
}

// ---------- kernel 1: weights -> bf16 [192][1024]; rows 64..127 (Wq) pre-scaled by 1/8
__global__ __launch_bounds__(256) void wconv_k(const float* __restrict__ Wk,
    const float* __restrict__ Wq, const float* __restrict__ Wv,
    __bf16* __restrict__ Wbf){
  int idx = blockIdx.x*256 + threadIdx.x;
  int e0 = idx*4;
  int n = e0 >> 10;
  int c = e0 & 1023;
  const float* src; float s;
  if (n < 64)      { src = Wk + (size_t)n*CDIM;       s = 1.0f;   }
  else if (n < 128){ src = Wq + (size_t)(n-64)*CDIM;  s = 0.125f; }
  else             { src = Wv + (size_t)(n-128)*CDIM; s = 1.0f;   }
  float4 v = *reinterpret_cast<const float4*>(src + c);
  __bf16* dst = Wbf + e0;
  dst[0]=(__bf16)(v.x*s); dst[1]=(__bf16)(v.y*s);
  dst[2]=(__bf16)(v.z*s); dst[3]=(__bf16)(v.w*s);
}

// ---------- kernel 2: projections, LDS-staged tiled GEMM, M-tile 32.
// grid 512 x 512 thr (8 waves) -> 2 blocks/CU, 16 waves/CU. K=1024 in 16 steps of 64.
// Wave (wr,wn): rows wr*16..+15 (1 frag), cols wn*48..+47 (3 frags); 6 MFMA/step.
// Next step's W/X global loads prefetched into registers.
__global__ __launch_bounds__(512) void proj_k(const float* __restrict__ x,
    const __bf16* __restrict__ Wbf, __bf16* __restrict__ kb,
    __bf16* __restrict__ qb, __bf16* __restrict__ vTb){
  __shared__ __bf16 Wt[192][72];    // 27.6 KB
  __shared__ __bf16 Xt[32][72];     //  4.6 KB

  const int tid  = threadIdx.x;
  const int lane = tid & 63;
  const int w    = tid >> 6;        // 0..7
  const int wr   = w >> 2;          // row half (16 rows each)
  const int wn   = w & 3;           // N quarter (48 cols each)
  const int l15  = lane & 15, g = lane >> 4;
  const long row0 = (long)blockIdx.x*32;

  // staging slots: W 3 chunks of bf16x8, X 1 float4
  const int wrw[3] = { tid>>3, (tid+512)>>3, (tid+1024)>>3 };
  const int wc8    = (tid & 7)*8;
  const int xrw = tid >> 4, xc4 = (tid & 15)*4;

  f32x4 acc[3];
  #pragma unroll
  for (int j=0;j<3;j++) acc[j] = (f32x4)(0.0f);

  bf16x8 wreg[3];
  float4 xreg;

  // prologue: load step 0
  #pragma unroll
  for (int i=0;i<3;i++)
    wreg[i] = *reinterpret_cast<const bf16x8*>(Wbf + (size_t)wrw[i]*CDIM + wc8);
  xreg = *reinterpret_cast<const float4*>(x + (row0 + xrw)*CDIM + xc4);

  for (int kk=0; kk<16; ++kk){
    __syncthreads();                       // prev step's LDS fully consumed
    #pragma unroll
    for (int i=0;i<3;i++)
      *reinterpret_cast<bf16x8*>(&Wt[wrw[i]][wc8]) = wreg[i];
    {
      bf16x4 xv;
      xv[0]=(__bf16)xreg.x; xv[1]=(__bf16)xreg.y;
      xv[2]=(__bf16)xreg.z; xv[3]=(__bf16)xreg.w;
      *reinterpret_cast<bf16x4*>(&Xt[xrw][xc4]) = xv;
    }
    __syncthreads();

    // issue NEXT step's global loads; latency hides under ds_read+MFMA + other waves
    if (kk < 15){
      const int nk0 = (kk+1)*64;
      #pragma unroll
      for (int i=0;i<3;i++)
        wreg[i] = *reinterpret_cast<const bf16x8*>(Wbf + (size_t)wrw[i]*CDIM + nk0 + wc8);
      xreg = *reinterpret_cast<const float4*>(x + (row0 + xrw)*CDIM + nk0 + xc4);
    }

    bf16x8 a0, a1, b0[3], b1[3];
    a0 = *reinterpret_cast<const bf16x8*>(&Xt[wr*16 + l15][g*8]);
    a1 = *reinterpret_cast<const bf16x8*>(&Xt[wr*16 + l15][g*8 + 32]);
    #pragma unroll
    for (int nf=0;nf<3;nf++){
      b0[nf] = *reinterpret_cast<const bf16x8*>(&Wt[wn*48 + nf*16 + l15][g*8]);
      b1[nf] = *reinterpret_cast<const bf16x8*>(&Wt[wn*48 + nf*16 + l15][g*8 + 32]);
    }
    #pragma unroll
    for (int nf=0;nf<3;nf++)
      acc[nf] = mfma16(a1, b1[nf], mfma16(a0, b0[nf], acc[nf]));
  }

  // epilogue: k,q row-major [BT][64]; v transposed [B][64][T]
  const long bidx = row0 >> 12;            // batch (32 | 4096, never crosses)
  #pragma unroll
  for (int nf=0;nf<3;nf++){
    const int n0  = wn*48 + nf*16 + l15;
    const int mat = n0 >> 6;               // 0=k, 1=q, 2=v
    const int h   = n0 & 63;
    const long rbase = row0 + wr*16 + g*4;
    if (mat == 0){
      #pragma unroll
      for (int r=0;r<4;r++) kb[(rbase+r)*HD + h] = (__bf16)acc[nf][r];
    } else if (mat == 1){
      #pragma unroll
      for (int r=0;r<4;r++) qb[(rbase+r)*HD + h] = (__bf16)acc[nf][r];
    } else {
      bf16x4 t4;
      #pragma unroll
      for (int r=0;r<4;r++) t4[r] = (__bf16)acc[nf][r];
      *reinterpret_cast<bf16x4*>(vTb + (bidx*64 + h)*TT + (rbase & 4095)) = t4;
    }
  }
}

// ---------- kernel 3: causal flash attention, fixed-max softmax, KV-split partials,
// register-prefetched K/V staging. grid = B*64*NS, 256 thr (4 waves x 16 q-rows).
template<int NS>
__global__ __launch_bounds__(256) void attn_part_k(const __bf16* __restrict__ kbg,
    const __bf16* __restrict__ qbg, const __bf16* __restrict__ vT,
    __bf16* __restrict__ po, float* __restrict__ pl){
  __shared__ __bf16 Klds[64][68];     // [key][dim]
  __shared__ __bf16 Vlds[64][68];     // [dim][key]  (from pre-transposed vT)
  __shared__ __bf16 Plds[4][16][68];  // per-wave P round-trip

  const int tid  = threadIdx.x;
  const int lane = tid & 63;
  const int w    = tid >> 6;
  const int l15  = lane & 15, g = lane >> 4;

  const int bi  = blockIdx.x;
  const int b   = bi / (64*NS);
  const int rem = bi % (64*NS);
  const int qt  = 63 - rem / NS;      // longest blocks dispatch first
  const int s   = rem % NS;

  const int ntiles = qt + 1;
  const int lo = ( s      * ntiles) / NS;
  const int hi = ((s + 1) * ntiles) / NS;
  const int pidx = (b*64 + qt)*NS + s;

  if (lo == hi){                      // empty split (block-uniform): weight 0
    if (l15 == 0){
      #pragma unroll
      for (int r=0;r<4;r++) pl[pidx*64 + w*16 + g*4 + r] = 0.0f;
    }
    return;
  }

  const long qbase = (long)b*TT + (long)qt*64;

  bf16x8 qf0, qf1;
  {
    const __bf16* src = qbg + (qbase + w*16 + l15)*HD + g*8;
    qf0 = *reinterpret_cast<const bf16x8*>(src);
    qf1 = *reinterpret_cast<const bf16x8*>(src + 32);
  }

  f32x4 o[4];
  #pragma unroll
  for (int ch=0; ch<4; ++ch) o[ch] = (f32x4)(0.0f);
  float lp[4] = {0.f, 0.f, 0.f, 0.f};

  const __bf16* vbase = vT + (size_t)b*64*TT;

  // staging slots
  const int skey = tid >> 2;          // K row / V dim
  const int sd0  = (tid & 3) * 16;
  bf16x8 kr0, kr1, vr0, vr1;

  // prologue: load tile `lo`
  {
    const long kvbase = (long)b*TT + (long)lo*64;
    const __bf16* ks = kbg + (kvbase + skey)*HD + sd0;
    kr0 = *reinterpret_cast<const bf16x8*>(ks);
    kr1 = *reinterpret_cast<const bf16x8*>(ks+8);
    const __bf16* vs = vbase + (size_t)skey*TT + lo*64 + sd0;
    vr0 = *reinterpret_cast<const bf16x8*>(vs);
    vr1 = *reinterpret_cast<const bf16x8*>(vs+8);
  }

  for (int kv=lo; kv<hi; ++kv){
    __syncthreads();                  // previous tile fully consumed
    *reinterpret_cast<bf16x8*>(&Klds[skey][sd0])   = kr0;
    *reinterpret_cast<bf16x8*>(&Klds[skey][sd0+8]) = kr1;
    *reinterpret_cast<bf16x8*>(&Vlds[skey][sd0])   = vr0;
    *reinterpret_cast<bf16x8*>(&Vlds[skey][sd0+8]) = vr1;
    __syncthreads();

    // issue NEXT tile's loads; latency hides under QK/softmax/PV below
    if (kv+1 < hi){
      const long nbase = (long)b*TT + (long)(kv+1)*64;
      const __bf16* ks = kbg + (nbase + skey)*HD + sd0;
      kr0 = *reinterpret_cast<const bf16x8*>(ks);
      kr1 = *reinterpret_cast<const bf16x8*>(ks+8);
      const __bf16* vs = vbase + (size_t)skey*TT + (kv+1)*64 + sd0;
      vr0 = *reinterpret_cast<const bf16x8*>(vs);
      vr1 = *reinterpret_cast<const bf16x8*>(vs+8);
    }

    // S - 16 = Q K^T - 16 (seed accumulator with -16)
    f32x4 sv[4];
    __builtin_amdgcn_s_setprio(1);
    #pragma unroll
    for (int c=0;c<4;c++){
      bf16x8 kb0 = *reinterpret_cast<const bf16x8*>(&Klds[c*16 + l15][g*8]);
      bf16x8 kb1 = *reinterpret_cast<const bf16x8*>(&Klds[c*16 + l15][g*8 + 32]);
      sv[c] = mfma16(qf0, kb0, (f32x4)(-16.0f));
      sv[c] = mfma16(qf1, kb1, sv[c]);
    }
    __builtin_amdgcn_s_setprio(0);

    if (kv == qt){   // diagonal tile: causal mask
      #pragma unroll
      for (int c=0;c<4;c++){
        const int key = c*16 + l15;
        #pragma unroll
        for (int r=0;r<4;r++){
          const int qr = w*16 + g*4 + r;
          if (key > qr) sv[c][r] = -1e30f;
        }
      }
    }

    // p = exp(s-16); accumulate per-lane row sums (reduced once at end)
    #pragma unroll
    for (int c=0;c<4;c++){
      #pragma unroll
      for (int r=0;r<4;r++) sv[c][r] = __expf(sv[c][r]);
    }
    #pragma unroll
    for (int r=0;r<4;r++)
      lp[r] += (sv[0][r] + sv[1][r]) + (sv[2][r] + sv[3][r]);

    // P -> per-wave LDS (C-layout) -> A-frags (wave-synchronous)
    #pragma unroll
    for (int c=0;c<4;c++){
      #pragma unroll
      for (int r=0;r<4;r++) Plds[w][g*4+r][c*16 + l15] = (__bf16)sv[c][r];
    }
    asm volatile("s_waitcnt lgkmcnt(0)" ::: "memory");
    __builtin_amdgcn_sched_barrier(0);
    bf16x8 pa0 = *reinterpret_cast<const bf16x8*>(&Plds[w][l15][g*8]);
    bf16x8 pa1 = *reinterpret_cast<const bf16x8*>(&Plds[w][l15][g*8 + 32]);

    __builtin_amdgcn_s_setprio(1);
    #pragma unroll
    for (int ch=0; ch<4; ++ch){
      bf16x8 vb0 = *reinterpret_cast<const bf16x8*>(&Vlds[ch*16 + l15][g*8]);
      bf16x8 vb1 = *reinterpret_cast<const bf16x8*>(&Vlds[ch*16 + l15][g*8 + 32]);
      o[ch] = mfma16(pa0, vb0, o[ch]);
      o[ch] = mfma16(pa1, vb1, o[ch]);
    }
    __builtin_amdgcn_s_setprio(0);
  }

  // one cross-lane reduce of l at the end
  float lr[4];
  #pragma unroll
  for (int r=0;r<4;r++){
    float v = lp[r];
    v += __shfl_xor(v, 1);
    v += __shfl_xor(v, 2);
    v += __shfl_xor(v, 4);
    v += __shfl_xor(v, 8);
    lr[r] = v;
  }
  float rl[4];
  #pragma unroll
  for (int r=0;r<4;r++) rl[r] = (lr[r] > 0.0f) ? 1.0f/lr[r] : 0.0f;

  __bf16* podst = po + (size_t)pidx*4096;
  #pragma unroll
  for (int ch=0; ch<4; ++ch){
    #pragma unroll
    for (int r=0;r<4;r++)
      podst[(w*16 + g*4 + r)*64 + ch*16 + l15] = (__bf16)(o[ch][r] * rl[r]);
  }
  if (l15 == 0){
    #pragma unroll
    for (int r=0;r<4;r++) pl[pidx*64 + w*16 + g*4 + r] = lr[r];
  }
}

// ---------- kernel 4: combine partials (common fixed max -> weights are just l).
template<int NS>
__global__ __launch_bounds__(256) void comb_k(const __bf16* __restrict__ po,
    const float* __restrict__ pl, float* __restrict__ out){
  const int idx   = blockIdx.x*256 + threadIdx.x;
  const int qrow  = idx >> 6;
  const int dim   = idx & 63;
  const int qtg   = qrow >> 6;
  const int rowin = qrow & 63;

  float num = 0.0f, den = 0.0f;
  #pragma unroll
  for (int s=0;s<NS;s++){
    const float l = pl[(qtg*NS + s)*64 + rowin];
    den += l;
    num += l * (float)po[(size_t)(qtg*NS + s)*4096 + rowin*64 + dim];
  }
  out[idx] = num / den;
}

extern "C" void kernel_launch(void* const* d_in, const int* in_sizes, int n_in,
                              void* d_out, int out_size, void* d_ws, size_t ws_size,
                              hipStream_t stream) {
  const float* x  = (const float*)d_in[0];
  const float* Wk = (const float*)d_in[2];
  const float* Wq = (const float*)d_in[3];
  const float* Wv = (const float*)d_in[4];
  float* out = (float*)d_out;

  char* ws = (char*)d_ws;
  __bf16* Wbf = (__bf16*)ws;                         // 384 KiB
  __bf16* kb  = (__bf16*)(ws + 393216);              // 2 MiB
  __bf16* qb  = (__bf16*)(ws + 2490368);             // 2 MiB
  __bf16* vTb = (__bf16*)(ws + 4587520);             // 2 MiB
  __bf16* po  = (__bf16*)(ws + 6684672);

  wconv_k<<<192, 256, 0, stream>>>(Wk, Wq, Wv, Wbf);
  proj_k <<<512, 512, 0, stream>>>(x, Wbf, kb, qb, vTb);

  const size_t need8 = 6684672ull + (size_t)2048*4096*2 + (size_t)2048*64*4;
  if (ws_size >= need8){
    float* pl = (float*)(ws + 6684672 + (size_t)2048*4096*2);
    attn_part_k<8><<<2048, 256, 0, stream>>>(kb, qb, vTb, po, pl);
    comb_k<8>    <<<4096, 256, 0, stream>>>(po, pl, out);
  } else {
    float* pl = (float*)(ws + 6684672 + (size_t)1024*4096*2);
    attn_part_k<4><<<1024, 256, 0, stream>>>(kb, qb, vTb, po, pl);
    comb_k<4>    <<<4096, 256, 0, stream>>>(po, pl, out);
  }
}

// Round 9
// 60.546 us; speedup vs baseline: 2.5819x; 1.0379x over previous
//
#include <hip/hip_runtime.h>
#include <hip/hip_bf16.h>

#define BT 16384      // B*T rows
#define CDIM 1024
#define HD 64
#define TT 4096

typedef __bf16 bf16x8 __attribute__((ext_vector_type(8)));
typedef __bf16 bf16x4 __attribute__((ext_vector_type(4)));
typedef float f32x4 __attribute__((ext_vector_type(4)));

__device__ __forceinline__ f32x4 mfma16(bf16x8 a, bf16x8 b, f32x4 c){
  return __builtin_amdgcn_mfma_f32_16x16x32_bf16(a, b, c, 0, 0, 0);
}

// ---------- kernel 1: weights -> bf16 [192][1024]; rows 64..127 (Wq) pre-scaled by 1/8
__global__ __launch_bounds__(256) void wconv_k(const float* __restrict__ Wk,
    const float* __restrict__ Wq, const float* __restrict__ Wv,
    __bf16* __restrict__ Wbf){
  int idx = blockIdx.x*256 + threadIdx.x;
  int e0 = idx*4;
  int n = e0 >> 10;
  int c = e0 & 1023;
  const float* src; float s;
  if (n < 64)      { src = Wk + (size_t)n*CDIM;       s = 1.0f;   }
  else if (n < 128){ src = Wq + (size_t)(n-64)*CDIM;  s = 0.125f; }
  else             { src = Wv + (size_t)(n-128)*CDIM; s = 1.0f;   }
  float4 v = *reinterpret_cast<const float4*>(src + c);
  __bf16* dst = Wbf + e0;
  dst[0]=(__bf16)(v.x*s); dst[1]=(__bf16)(v.y*s);
  dst[2]=(__bf16)(v.z*s); dst[3]=(__bf16)(v.w*s);
}

// ---------- kernel 2: projections, single-barrier double-buffered tiled GEMM.
// grid 512 x 512 thr (8 waves), M-tile 32, K=1024 in 16 steps of 64.
// iter t: ds_write regs(t+1)->buf[nxt] (loads issued a full iter ago),
//         issue loads(t+2)->regs, compute buf[cur], ONE barrier.
__global__ __launch_bounds__(512) void proj_k(const float* __restrict__ x,
    const __bf16* __restrict__ Wbf, __bf16* __restrict__ kb,
    __bf16* __restrict__ qb, __bf16* __restrict__ vTb){
  __shared__ __bf16 Wt[2][192][68];   // 51.0 KB
  __shared__ __bf16 Xt[2][32][68];    //  8.5 KB

  const int tid  = threadIdx.x;
  const int lane = tid & 63;
  const int w    = tid >> 6;        // 0..7
  const int wr   = w >> 2;          // row half (16 rows each)
  const int wn   = w & 3;           // N quarter (48 cols each)
  const int l15  = lane & 15, g = lane >> 4;
  const long row0 = (long)blockIdx.x*32;

  // staging slots: W 3 chunks of bf16x8, X 1 float4
  const int wrw0 = tid>>3, wrw1 = (tid+512)>>3, wrw2 = (tid+1024)>>3;
  const int wc8  = (tid & 7)*8;
  const int xrw  = tid >> 4, xc4 = (tid & 15)*4;

  const float*  xsrc = x + (row0 + xrw)*CDIM + xc4;
  const __bf16* ws0  = Wbf + (size_t)wrw0*CDIM + wc8;
  const __bf16* ws1  = Wbf + (size_t)wrw1*CDIM + wc8;
  const __bf16* ws2  = Wbf + (size_t)wrw2*CDIM + wc8;

  f32x4 acc[3];
  #pragma unroll
  for (int j=0;j<3;j++) acc[j] = (f32x4)(0.0f);

  bf16x8 w0, w1, w2; float4 xr;

  // prologue: tile 0 -> regs -> buf0; tile 1 -> regs; barrier
  w0 = *reinterpret_cast<const bf16x8*>(ws0);
  w1 = *reinterpret_cast<const bf16x8*>(ws1);
  w2 = *reinterpret_cast<const bf16x8*>(ws2);
  xr = *reinterpret_cast<const float4*>(xsrc);
  *reinterpret_cast<bf16x8*>(&Wt[0][wrw0][wc8]) = w0;
  *reinterpret_cast<bf16x8*>(&Wt[0][wrw1][wc8]) = w1;
  *reinterpret_cast<bf16x8*>(&Wt[0][wrw2][wc8]) = w2;
  {
    bf16x4 xv;
    xv[0]=(__bf16)xr.x; xv[1]=(__bf16)xr.y; xv[2]=(__bf16)xr.z; xv[3]=(__bf16)xr.w;
    *reinterpret_cast<bf16x4*>(&Xt[0][xrw][xc4]) = xv;
  }
  w0 = *reinterpret_cast<const bf16x8*>(ws0 + 64);
  w1 = *reinterpret_cast<const bf16x8*>(ws1 + 64);
  w2 = *reinterpret_cast<const bf16x8*>(ws2 + 64);
  xr = *reinterpret_cast<const float4*>(xsrc + 64);
  __syncthreads();

  #pragma unroll 2
  for (int t=0; t<16; ++t){
    const int cur = t & 1, nxt = cur ^ 1;

    // (a) write tile t+1 (regs were loaded a full iteration ago)
    if (t+1 < 16){
      *reinterpret_cast<bf16x8*>(&Wt[nxt][wrw0][wc8]) = w0;
      *reinterpret_cast<bf16x8*>(&Wt[nxt][wrw1][wc8]) = w1;
      *reinterpret_cast<bf16x8*>(&Wt[nxt][wrw2][wc8]) = w2;
      bf16x4 xv;
      xv[0]=(__bf16)xr.x; xv[1]=(__bf16)xr.y; xv[2]=(__bf16)xr.z; xv[3]=(__bf16)xr.w;
      *reinterpret_cast<bf16x4*>(&Xt[nxt][xrw][xc4]) = xv;
    }
    // (b) issue tile t+2 loads (consumed 2 iterations from now)
    if (t+2 < 16){
      const int nk0 = (t+2)*64;
      w0 = *reinterpret_cast<const bf16x8*>(ws0 + nk0);
      w1 = *reinterpret_cast<const bf16x8*>(ws1 + nk0);
      w2 = *reinterpret_cast<const bf16x8*>(ws2 + nk0);
      xr = *reinterpret_cast<const float4*>(xsrc + nk0);
    }
    // (c) compute tile t from buf[cur]
    {
      bf16x8 a0, a1, b0[3], b1[3];
      a0 = *reinterpret_cast<const bf16x8*>(&Xt[cur][wr*16 + l15][g*8]);
      a1 = *reinterpret_cast<const bf16x8*>(&Xt[cur][wr*16 + l15][g*8 + 32]);
      #pragma unroll
      for (int nf=0;nf<3;nf++){
        b0[nf] = *reinterpret_cast<const bf16x8*>(&Wt[cur][wn*48 + nf*16 + l15][g*8]);
        b1[nf] = *reinterpret_cast<const bf16x8*>(&Wt[cur][wn*48 + nf*16 + l15][g*8 + 32]);
      }
      #pragma unroll
      for (int nf=0;nf<3;nf++)
        acc[nf] = mfma16(a1, b1[nf], mfma16(a0, b0[nf], acc[nf]));
    }
    // (d) one barrier per step
    __syncthreads();
  }

  // epilogue: k,q row-major [BT][64]; v transposed [B][64][T]
  const long bidx = row0 >> 12;            // batch (32 | 4096, never crosses)
  #pragma unroll
  for (int nf=0;nf<3;nf++){
    const int n0  = wn*48 + nf*16 + l15;
    const int mat = n0 >> 6;               // 0=k, 1=q, 2=v
    const int h   = n0 & 63;
    const long rbase = row0 + wr*16 + g*4;
    if (mat == 0){
      #pragma unroll
      for (int r=0;r<4;r++) kb[(rbase+r)*HD + h] = (__bf16)acc[nf][r];
    } else if (mat == 1){
      #pragma unroll
      for (int r=0;r<4;r++) qb[(rbase+r)*HD + h] = (__bf16)acc[nf][r];
    } else {
      bf16x4 t4;
      #pragma unroll
      for (int r=0;r<4;r++) t4[r] = (__bf16)acc[nf][r];
      *reinterpret_cast<bf16x4*>(vTb + (bidx*64 + h)*TT + (rbase & 4095)) = t4;
    }
  }
}

// ---------- kernel 3: causal flash attention, fixed-max softmax, KV-split partials,
// register-prefetched K/V staging. grid = B*64*NS, 256 thr (4 waves x 16 q-rows).
template<int NS>
__global__ __launch_bounds__(256) void attn_part_k(const __bf16* __restrict__ kbg,
    const __bf16* __restrict__ qbg, const __bf16* __restrict__ vT,
    __bf16* __restrict__ po, float* __restrict__ pl){
  __shared__ __bf16 Klds[64][68];     // [key][dim]
  __shared__ __bf16 Vlds[64][68];     // [dim][key]  (from pre-transposed vT)
  __shared__ __bf16 Plds[4][16][68];  // per-wave P round-trip

  const int tid  = threadIdx.x;
  const int lane = tid & 63;
  const int w    = tid >> 6;
  const int l15  = lane & 15, g = lane >> 4;

  const int bi  = blockIdx.x;
  const int b   = bi / (64*NS);
  const int rem = bi % (64*NS);
  const int qt  = 63 - rem / NS;      // longest blocks dispatch first
  const int s   = rem % NS;

  const int ntiles = qt + 1;
  const int lo = ( s      * ntiles) / NS;
  const int hi = ((s + 1) * ntiles) / NS;
  const int pidx = (b*64 + qt)*NS + s;

  if (lo == hi){                      // empty split (block-uniform): weight 0
    if (l15 == 0){
      #pragma unroll
      for (int r=0;r<4;r++) pl[pidx*64 + w*16 + g*4 + r] = 0.0f;
    }
    return;
  }

  const long qbase = (long)b*TT + (long)qt*64;

  bf16x8 qf0, qf1;
  {
    const __bf16* src = qbg + (qbase + w*16 + l15)*HD + g*8;
    qf0 = *reinterpret_cast<const bf16x8*>(src);
    qf1 = *reinterpret_cast<const bf16x8*>(src + 32);
  }

  f32x4 o[4];
  #pragma unroll
  for (int ch=0; ch<4; ++ch) o[ch] = (f32x4)(0.0f);
  float lp[4] = {0.f, 0.f, 0.f, 0.f};

  const __bf16* vbase = vT + (size_t)b*64*TT;

  // staging slots
  const int skey = tid >> 2;          // K row / V dim
  const int sd0  = (tid & 3) * 16;
  bf16x8 kr0, kr1, vr0, vr1;

  // prologue: load tile `lo`
  {
    const long kvbase = (long)b*TT + (long)lo*64;
    const __bf16* ks = kbg + (kvbase + skey)*HD + sd0;
    kr0 = *reinterpret_cast<const bf16x8*>(ks);
    kr1 = *reinterpret_cast<const bf16x8*>(ks+8);
    const __bf16* vs = vbase + (size_t)skey*TT + lo*64 + sd0;
    vr0 = *reinterpret_cast<const bf16x8*>(vs);
    vr1 = *reinterpret_cast<const bf16x8*>(vs+8);
  }

  for (int kv=lo; kv<hi; ++kv){
    __syncthreads();                  // previous tile fully consumed
    *reinterpret_cast<bf16x8*>(&Klds[skey][sd0])   = kr0;
    *reinterpret_cast<bf16x8*>(&Klds[skey][sd0+8]) = kr1;
    *reinterpret_cast<bf16x8*>(&Vlds[skey][sd0])   = vr0;
    *reinterpret_cast<bf16x8*>(&Vlds[skey][sd0+8]) = vr1;
    __syncthreads();

    // issue NEXT tile's loads; latency hides under QK/softmax/PV below
    if (kv+1 < hi){
      const long nbase = (long)b*TT + (long)(kv+1)*64;
      const __bf16* ks = kbg + (nbase + skey)*HD + sd0;
      kr0 = *reinterpret_cast<const bf16x8*>(ks);
      kr1 = *reinterpret_cast<const bf16x8*>(ks+8);
      const __bf16* vs = vbase + (size_t)skey*TT + (kv+1)*64 + sd0;
      vr0 = *reinterpret_cast<const bf16x8*>(vs);
      vr1 = *reinterpret_cast<const bf16x8*>(vs+8);
    }

    // S - 16 = Q K^T - 16 (seed accumulator with -16)
    f32x4 sv[4];
    __builtin_amdgcn_s_setprio(1);
    #pragma unroll
    for (int c=0;c<4;c++){
      bf16x8 kb0 = *reinterpret_cast<const bf16x8*>(&Klds[c*16 + l15][g*8]);
      bf16x8 kb1 = *reinterpret_cast<const bf16x8*>(&Klds[c*16 + l15][g*8 + 32]);
      sv[c] = mfma16(qf0, kb0, (f32x4)(-16.0f));
      sv[c] = mfma16(qf1, kb1, sv[c]);
    }
    __builtin_amdgcn_s_setprio(0);

    if (kv == qt){   // diagonal tile: causal mask
      #pragma unroll
      for (int c=0;c<4;c++){
        const int key = c*16 + l15;
        #pragma unroll
        for (int r=0;r<4;r++){
          const int qr = w*16 + g*4 + r;
          if (key > qr) sv[c][r] = -1e30f;
        }
      }
    }

    // p = exp(s-16); accumulate per-lane row sums (reduced once at end)
    #pragma unroll
    for (int c=0;c<4;c++){
      #pragma unroll
      for (int r=0;r<4;r++) sv[c][r] = __expf(sv[c][r]);
    }
    #pragma unroll
    for (int r=0;r<4;r++)
      lp[r] += (sv[0][r] + sv[1][r]) + (sv[2][r] + sv[3][r]);

    // P -> per-wave LDS (C-layout) -> A-frags (wave-synchronous)
    #pragma unroll
    for (int c=0;c<4;c++){
      #pragma unroll
      for (int r=0;r<4;r++) Plds[w][g*4+r][c*16 + l15] = (__bf16)sv[c][r];
    }
    asm volatile("s_waitcnt lgkmcnt(0)" ::: "memory");
    __builtin_amdgcn_sched_barrier(0);
    bf16x8 pa0 = *reinterpret_cast<const bf16x8*>(&Plds[w][l15][g*8]);
    bf16x8 pa1 = *reinterpret_cast<const bf16x8*>(&Plds[w][l15][g*8 + 32]);

    __builtin_amdgcn_s_setprio(1);
    #pragma unroll
    for (int ch=0; ch<4; ++ch){
      bf16x8 vb0 = *reinterpret_cast<const bf16x8*>(&Vlds[ch*16 + l15][g*8]);
      bf16x8 vb1 = *reinterpret_cast<const bf16x8*>(&Vlds[ch*16 + l15][g*8 + 32]);
      o[ch] = mfma16(pa0, vb0, o[ch]);
      o[ch] = mfma16(pa1, vb1, o[ch]);
    }
    __builtin_amdgcn_s_setprio(0);
  }

  // one cross-lane reduce of l at the end
  float lr[4];
  #pragma unroll
  for (int r=0;r<4;r++){
    float v = lp[r];
    v += __shfl_xor(v, 1);
    v += __shfl_xor(v, 2);
    v += __shfl_xor(v, 4);
    v += __shfl_xor(v, 8);
    lr[r] = v;
  }
  float rl[4];
  #pragma unroll
  for (int r=0;r<4;r++) rl[r] = (lr[r] > 0.0f) ? 1.0f/lr[r] : 0.0f;

  __bf16* podst = po + (size_t)pidx*4096;
  #pragma unroll
  for (int ch=0; ch<4; ++ch){
    #pragma unroll
    for (int r=0;r<4;r++)
      podst[(w*16 + g*4 + r)*64 + ch*16 + l15] = (__bf16)(o[ch][r] * rl[r]);
  }
  if (l15 == 0){
    #pragma unroll
    for (int r=0;r<4;r++) pl[pidx*64 + w*16 + g*4 + r] = lr[r];
  }
}

// ---------- kernel 4: combine partials (common fixed max -> weights are just l).
template<int NS>
__global__ __launch_bounds__(256) void comb_k(const __bf16* __restrict__ po,
    const float* __restrict__ pl, float* __restrict__ out){
  const int idx   = blockIdx.x*256 + threadIdx.x;
  const int qrow  = idx >> 6;
  const int dim   = idx & 63;
  const int qtg   = qrow >> 6;
  const int rowin = qrow & 63;

  float num = 0.0f, den = 0.0f;
  #pragma unroll
  for (int s=0;s<NS;s++){
    const float l = pl[(qtg*NS + s)*64 + rowin];
    den += l;
    num += l * (float)po[(size_t)(qtg*NS + s)*4096 + rowin*64 + dim];
  }
  out[idx] = num / den;
}

extern "C" void kernel_launch(void* const* d_in, const int* in_sizes, int n_in,
                              void* d_out, int out_size, void* d_ws, size_t ws_size,
                              hipStream_t stream) {
  const float* x  = (const float*)d_in[0];
  const float* Wk = (const float*)d_in[2];
  const float* Wq = (const float*)d_in[3];
  const float* Wv = (const float*)d_in[4];
  float* out = (float*)d_out;

  char* ws = (char*)d_ws;
  __bf16* Wbf = (__bf16*)ws;                         // 384 KiB
  __bf16* kb  = (__bf16*)(ws + 393216);              // 2 MiB
  __bf16* qb  = (__bf16*)(ws + 2490368);             // 2 MiB
  __bf16* vTb = (__bf16*)(ws + 4587520);             // 2 MiB
  __bf16* po  = (__bf16*)(ws + 6684672);

  wconv_k<<<192, 256, 0, stream>>>(Wk, Wq, Wv, Wbf);
  proj_k <<<512, 512, 0, stream>>>(x, Wbf, kb, qb, vTb);

  const size_t need8 = 6684672ull + (size_t)2048*4096*2 + (size_t)2048*64*4;
  if (ws_size >= need8){
    float* pl = (float*)(ws + 6684672 + (size_t)2048*4096*2);
    attn_part_k<8><<<2048, 256, 0, stream>>>(kb, qb, vTb, po, pl);
    comb_k<8>    <<<4096, 256, 0, stream>>>(po, pl, out);
  } else {
    float* pl = (float*)(ws + 6684672 + (size_t)1024*4096*2);
    attn_part_k<4><<<1024, 256, 0, stream>>>(kb, qb, vTb, po, pl);
    comb_k<4>    <<<4096, 256, 0, stream>>>(po, pl, out);
  }
}